// Round 5
// baseline (855.543 us; speedup 1.0000x reference)
//
#include <hip/hip_runtime.h>
#include <math.h>

#define NN 100000
#define FIN 27
#define EMB 64
#define HH 128
#define LAYERS 4
#define GG 512
#define SCAN_CHUNK 2048   // 256 threads x 8 elements
#define SPAN 512          // nodes per bucket
#define SPANSHIFT 9
#define MAXNB 256
#define ECAP 16384        // per-bucket edge slab capacity (mean ~8163)
#define LPAD_US 136       // LDS row stride in ushorts: 272B, 16B-aligned rows
#define TM 64             // rows per gru block (4 m-tiles of 16)

typedef __attribute__((ext_vector_type(8))) short short8;
typedef __attribute__((ext_vector_type(4))) float floatx4;

__device__ __forceinline__ float sigmf(float x) { return 1.0f / (1.0f + __expf(-x)); }
__device__ __forceinline__ float tanhfast(float x) { return 1.0f - 2.0f / (__expf(2.0f * x) + 1.0f); }

__device__ __forceinline__ unsigned short f2bf(float f) {
    unsigned int u = __float_as_uint(f);
    u += 0x7FFFu + ((u >> 16) & 1u);
    return (unsigned short)(u >> 16);
}

__device__ __forceinline__ float bflo(unsigned int v) { return __uint_as_float(v << 16); }
__device__ __forceinline__ float bfhi(unsigned int v) { return __uint_as_float(v & 0xFFFF0000u); }
__device__ __forceinline__ float bfs(unsigned short v) { return __uint_as_float(((unsigned)v) << 16); }

// x1 = sigmoid(x @ lin0_w) (fp32, exact output); h = x1 in bf16 (lower 64 ch only;
// upper half is never read: agg<HALF> reads 128B rows, gru<HALF> masks c>=64).
__global__ void lin0_kernel(const float* __restrict__ x, const float* __restrict__ w,
                            float* __restrict__ x1_out, unsigned short* __restrict__ hbf, int n) {
    int wave = (int)((blockIdx.x * blockDim.x + threadIdx.x) >> 6);
    int lane = threadIdx.x & 63;
    if (wave >= n) return;
    const float* xr = x + (size_t)wave * FIN;
    float acc = 0.0f;
#pragma unroll
    for (int k = 0; k < FIN; ++k) acc += xr[k] * w[k * EMB + lane];
    float v = 1.0f / (1.0f + expf(-acc));
    x1_out[(size_t)wave * EMB + lane] = v;
    hbf[(size_t)wave * HH + lane] = f2bf(v);
}

// Direct-reservation bucketed scatter: one pass over edges. Per-block LDS hist,
// one global atomic per (block,bucket), packed (dst_local<<17)|src into slab b*ECAP.
__global__ void bucket_scatter_direct(const int* __restrict__ src, const int* __restrict__ dst,
                                      int* __restrict__ bucket_cnt, unsigned* __restrict__ ebuf,
                                      int e) {
    __shared__ int lh[MAXNB];
    __shared__ int gb[MAXNB];
    int t = threadIdx.x;  // 1024
    for (int i = t; i < MAXNB; i += 1024) lh[i] = 0;
    __syncthreads();
    int base = blockIdx.x * 16384;
    int lidx[16], sv[16], dv[16];
#pragma unroll
    for (int i = 0; i < 16; ++i) {
        int eid = base + i * 1024 + t;
        if (eid < e) {
            sv[i] = src[eid];
            dv[i] = dst[eid];
            lidx[i] = atomicAdd(&lh[dv[i] >> SPANSHIFT], 1);
        } else lidx[i] = -1;
    }
    __syncthreads();
    for (int i = t; i < MAXNB; i += 1024) {
        int c = lh[i];
        gb[i] = c ? atomicAdd(&bucket_cnt[i], c) : 0;
    }
    __syncthreads();
#pragma unroll
    for (int i = 0; i < 16; ++i) {
        if (lidx[i] >= 0) {
            int b = dv[i] >> SPANSHIFT;
            int pos = gb[b] + lidx[i];
            if (pos < ECAP) {
                unsigned dl = (unsigned)(dv[i] - (b << SPANSHIFT));
                ebuf[(size_t)b * ECAP + pos] = (dl << 17) | (unsigned)sv[i];
            }
        }
    }
}

// Per-node degree via per-bucket LDS histogram.
__global__ void deg_from_buckets(const unsigned* __restrict__ ebuf, const int* __restrict__ bucket_cnt,
                                 int* __restrict__ deg, int n) {
    __shared__ int ld[SPAN];
    int b = blockIdx.x, t = threadIdx.x;  // 256
    ld[t] = 0; ld[t + 256] = 0;
    __syncthreads();
    int cnt = bucket_cnt[b];
    if (cnt > ECAP) cnt = ECAP;
    size_t base = (size_t)b * ECAP;
    int nodebase = b << SPANSHIFT;
    for (int j = t; j < cnt; j += 256)
        atomicAdd(&ld[ebuf[base + j] >> 17], 1);
    __syncthreads();
    int i0 = nodebase + t, i1 = nodebase + 256 + t;
    if (i0 < n) deg[i0] = ld[t];
    if (i1 < n) deg[i1] = ld[t + 256];
}

// ---- multi-block exclusive scan of deg -> rowptr ----
__global__ void scan_partial(const int* __restrict__ deg, int* __restrict__ blocksum, int n) {
    int b = blockIdx.x, t = threadIdx.x;
    int base = b * SCAN_CHUNK + t * 8;
    int s = 0;
#pragma unroll
    for (int i = 0; i < 8; ++i) {
        int idx = base + i;
        if (idx < n) s += deg[idx];
    }
#pragma unroll
    for (int off = 32; off > 0; off >>= 1) s += __shfl_down(s, off, 64);
    __shared__ int ws[4];
    if ((t & 63) == 0) ws[t >> 6] = s;
    __syncthreads();
    if (t == 0) blocksum[b] = ws[0] + ws[1] + ws[2] + ws[3];
}

__global__ void scan_blocksums(const int* __restrict__ blocksum, int* __restrict__ blockoff, int nb) {
    int t = threadIdx.x;
    int own = (t < nb) ? blocksum[t] : 0;
    int v = own;
    for (int off = 1; off < 64; off <<= 1) {
        int u = __shfl_up(v, off, 64);
        if (t >= off) v += u;
    }
    if (t < nb) blockoff[t] = v - own;
}

__global__ void scan_final(const int* __restrict__ deg, const int* __restrict__ blockoff,
                           int* __restrict__ rowptr, int n) {
    int b = blockIdx.x, t = threadIdx.x;
    int base = b * SCAN_CHUNK + t * 8;
    int v[8];
    int s = 0;
#pragma unroll
    for (int i = 0; i < 8; ++i) {
        int idx = base + i;
        v[i] = (idx < n) ? deg[idx] : 0;
        s += v[i];
    }
    __shared__ int ts[256];
    ts[t] = s;
    __syncthreads();
    for (int off = 1; off < 256; off <<= 1) {
        int u = (t >= off) ? ts[t - off] : 0;
        __syncthreads();
        ts[t] += u;
        __syncthreads();
    }
    int run = blockoff[b] + ((t == 0) ? 0 : ts[t - 1]);
#pragma unroll
    for (int i = 0; i < 8; ++i) {
        int idx = base + i;
        if (idx < n) {
            rowptr[idx] = run;
            run += v[i];
        } else if (idx == n) {
            rowptr[n] = run;
        }
    }
}

// Place edges into CSR col with LDS cursors; writes confined to ~32KB/bucket.
__global__ void place_kernel(const unsigned* __restrict__ ebuf, const int* __restrict__ bucket_cnt,
                             const int* __restrict__ rowptr, int* __restrict__ col, int n) {
    __shared__ int cur[SPAN];
    int b = blockIdx.x, t = threadIdx.x;  // 256
    int nodebase = b << SPANSHIFT;
    int i0 = nodebase + t, i1 = nodebase + 256 + t;
    cur[t] = (i0 < n) ? rowptr[i0] : 0;
    cur[t + 256] = (i1 < n) ? rowptr[i1] : 0;
    __syncthreads();
    int cnt = bucket_cnt[b];
    if (cnt > ECAP) cnt = ECAP;
    size_t base = (size_t)b * ECAP;
    for (int j = t; j < cnt; j += 256) {
        unsigned ed = ebuf[base + j];
        int pos = atomicAdd(&cur[ed >> 17], 1);
        col[pos] = (int)(ed & 0x1FFFFu);
    }
}

// Pure gather-aggregate: one wave per node, agg row written bf16 to aggout.
// HALF=1: h rows have upper 64 ch == 0 -> read only 128B/row via uint2.
// At the L3->L2 random-fill ceiling (~2.9-3.4 TB/s; FETCH = 8 XCD x h-size replication).
template <int HALF>
__global__ __launch_bounds__(512, 8)
void agg_kernel(const unsigned short* __restrict__ hin, unsigned short* __restrict__ aggout,
                const int* __restrict__ rowptr, const int* __restrict__ col, int n) {
    int node = (int)((blockIdx.x * blockDim.x + threadIdx.x) >> 6);
    int lane = threadIdx.x & 63;
    if (node >= n) return;
    int l16 = lane & 15;
    int lg = lane >> 4;
    const uint4* hin4 = (const uint4*)hin;
    const uint2* hin2 = (const uint2*)hin;
    int r0 = rowptr[node];
    int r1 = rowptr[node + 1];

    if (HALF) {
        float a[4], b[4];
#pragma unroll
        for (int k = 0; k < 4; ++k) { a[k] = 0.0f; b[k] = 0.0f; }
        int j = r0 + lg;
        for (; j + 4 < r1; j += 8) {
            int s0 = col[j], s1 = col[j + 4];
            uint2 v0 = hin2[(size_t)s0 * 32 + l16];
            uint2 v1 = hin2[(size_t)s1 * 32 + l16];
            a[0] += bflo(v0.x); a[1] += bfhi(v0.x);
            a[2] += bflo(v0.y); a[3] += bfhi(v0.y);
            b[0] += bflo(v1.x); b[1] += bfhi(v1.x);
            b[2] += bflo(v1.y); b[3] += bfhi(v1.y);
        }
        for (; j < r1; j += 4) {
            int s = col[j];
            uint2 v = hin2[(size_t)s * 32 + l16];
            a[0] += bflo(v.x); a[1] += bfhi(v.x);
            a[2] += bflo(v.y); a[3] += bfhi(v.y);
        }
#pragma unroll
        for (int k = 0; k < 4; ++k) {
            a[k] += b[k];
            a[k] += __shfl_xor(a[k], 32, 64);
            a[k] += __shfl_xor(a[k], 16, 64);
        }
        if (lg == 0) {
            uint2 o;
            o.x = (unsigned)f2bf(a[0]) | ((unsigned)f2bf(a[1]) << 16);
            o.y = (unsigned)f2bf(a[2]) | ((unsigned)f2bf(a[3]) << 16);
            *(uint2*)(aggout + (size_t)node * HH + l16 * 4) = o;
        }
    } else {
        float a[8], b[8];
#pragma unroll
        for (int k = 0; k < 8; ++k) { a[k] = 0.0f; b[k] = 0.0f; }
        int j = r0 + lg;
        for (; j + 12 < r1; j += 16) {
            int s0 = col[j], s1 = col[j + 4], s2 = col[j + 8], s3 = col[j + 12];
            uint4 v0 = hin4[(size_t)s0 * 16 + l16];
            uint4 v1 = hin4[(size_t)s1 * 16 + l16];
            uint4 v2 = hin4[(size_t)s2 * 16 + l16];
            uint4 v3 = hin4[(size_t)s3 * 16 + l16];
            a[0] += bflo(v0.x); a[1] += bfhi(v0.x);
            a[2] += bflo(v0.y); a[3] += bfhi(v0.y);
            a[4] += bflo(v0.z); a[5] += bfhi(v0.z);
            a[6] += bflo(v0.w); a[7] += bfhi(v0.w);
            b[0] += bflo(v1.x); b[1] += bfhi(v1.x);
            b[2] += bflo(v1.y); b[3] += bfhi(v1.y);
            b[4] += bflo(v1.z); b[5] += bfhi(v1.z);
            b[6] += bflo(v1.w); b[7] += bfhi(v1.w);
            a[0] += bflo(v2.x); a[1] += bfhi(v2.x);
            a[2] += bflo(v2.y); a[3] += bfhi(v2.y);
            a[4] += bflo(v2.z); a[5] += bfhi(v2.z);
            a[6] += bflo(v2.w); a[7] += bfhi(v2.w);
            b[0] += bflo(v3.x); b[1] += bfhi(v3.x);
            b[2] += bflo(v3.y); b[3] += bfhi(v3.y);
            b[4] += bflo(v3.z); b[5] += bfhi(v3.z);
            b[6] += bflo(v3.w); b[7] += bfhi(v3.w);
        }
        for (; j + 4 < r1; j += 8) {
            int s0 = col[j], s1 = col[j + 4];
            uint4 v0 = hin4[(size_t)s0 * 16 + l16];
            uint4 v1 = hin4[(size_t)s1 * 16 + l16];
            a[0] += bflo(v0.x); a[1] += bfhi(v0.x);
            a[2] += bflo(v0.y); a[3] += bfhi(v0.y);
            a[4] += bflo(v0.z); a[5] += bfhi(v0.z);
            a[6] += bflo(v0.w); a[7] += bfhi(v0.w);
            b[0] += bflo(v1.x); b[1] += bfhi(v1.x);
            b[2] += bflo(v1.y); b[3] += bfhi(v1.y);
            b[4] += bflo(v1.z); b[5] += bfhi(v1.z);
            b[6] += bflo(v1.w); b[7] += bfhi(v1.w);
        }
        for (; j < r1; j += 4) {
            int s = col[j];
            uint4 v = hin4[(size_t)s * 16 + l16];
            a[0] += bflo(v.x); a[1] += bfhi(v.x);
            a[2] += bflo(v.y); a[3] += bfhi(v.y);
            a[4] += bflo(v.z); a[5] += bfhi(v.z);
            a[6] += bflo(v.w); a[7] += bfhi(v.w);
        }
#pragma unroll
        for (int k = 0; k < 8; ++k) {
            a[k] += b[k];
            a[k] += __shfl_xor(a[k], 32, 64);
            a[k] += __shfl_xor(a[k], 16, 64);
        }
        if (lg == 0) {
            uint4 o;
            o.x = (unsigned)f2bf(a[0]) | ((unsigned)f2bf(a[1]) << 16);
            o.y = (unsigned)f2bf(a[2]) | ((unsigned)f2bf(a[3]) << 16);
            o.z = (unsigned)f2bf(a[4]) | ((unsigned)f2bf(a[5]) << 16);
            o.w = (unsigned)f2bf(a[6]) | ((unsigned)f2bf(a[7]) << 16);
            *(uint4*)(aggout + (size_t)node * HH + l16 * 8) = o;
        }
    }
}

// GEMM + GRU epilogue, TM=64, 1024 thr (16 waves: mg 2 x w8 8), accs 48 VGPR.
// KEY CHANGE vs R1-R3 (all pinned at ~60-66us regardless of tiling/occupancy):
// B-fragments no longer stream L2->L1->VGPR per wave (per-CU vector-load path was
// the invariant bottleneck). Instead B is staged cooperatively into LDS in 24KB
// half-kt slices (one matrix x one kt x 24 ct-tiles), double-buffered via regs
// (T14 async-split: ds_write slice s; barrier; prefetch s+1 into regs overlapped
// with MFMA of s; barrier). Each B byte enters the CU exactly once. A-fragments
// and h_prev are read directly from global (L2-resident). h_new transposed
// through the freed LDS buffer for coalesced stores.
template <int HALF>
__global__ __launch_bounds__(1024, 4)
void gru_kernel(const unsigned short* __restrict__ aggin,
                const unsigned short* __restrict__ hin,
                unsigned short* __restrict__ hout,
                const unsigned short* __restrict__ Wfp,
                const unsigned short* __restrict__ whhp,
                const float* __restrict__ b_ih, const float* __restrict__ b_hh,
                int n) {
    __shared__ unsigned short Bb[2][12288];   // 2 x 24KB B slices; Bb[0] reused as store staging
    int tid = threadIdx.x;
    int wave = tid >> 6;       // 0..15
    int lane = tid & 63;
    int quad = lane >> 4;
    int l15 = lane & 15;
    int w8 = wave & 7;         // ct group
    int mg = wave >> 3;        // m-tile pair: rows [mg*32, mg*32+32)
    int M0 = blockIdx.x * TM;
    if (M0 >= n) return;

    const int KTMAX = HALF ? 2 : 4;
    const int NSLICE = 2 * KTMAX;   // slice s: mat = s&1 (0=Wf,1=whh), kt = s>>1

    floatx4 gi[2][3], gh[2][3];
#pragma unroll
    for (int m = 0; m < 2; ++m)
#pragma unroll
        for (int g = 0; g < 3; ++g) {
            gi[m][g] = (floatx4)0.0f;
            gh[m][g] = (floatx4)0.0f;
        }

    // A-fragment row indices (clamped; OOB rows compute garbage, store is guarded)
    int ra0 = min(M0 + mg * 32 + l15, n - 1);
    int ra1 = min(M0 + mg * 32 + 16 + l15, n - 1);

    // preload slice 0 (Wfp, kt=0) into regs: 1536 uint4 over 1024 threads
    uint4 r0, r1;
    {
        const uint4* s4 = (const uint4*)Wfp;
        r0 = s4[tid];
        if (tid < 512) r1 = s4[tid + 1024];
    }

#pragma unroll
    for (int s = 0; s < NSLICE; ++s) {
        unsigned short* db = Bb[s & 1];
        // commit slice s to LDS (buf (s&1) last read at slice s-2; iter s-1's barrier orders it)
        *(uint4*)(db + (size_t)tid * 8) = r0;
        if (tid < 512) *(uint4*)(db + (size_t)(tid + 1024) * 8) = r1;
        __syncthreads();
        // prefetch slice s+1 into regs; HBM/L2 latency hides under MFMAs below
        if (s + 1 < NSLICE) {
            const unsigned short* nsrc = (((s + 1) & 1) ? whhp : Wfp) + ((s + 1) >> 1) * 12288;
            const uint4* s4 = (const uint4*)nsrc;
            r0 = s4[tid];
            if (tid < 512) r1 = s4[tid + 1024];
        }
        int mat = s & 1, kt = s >> 1;
        const unsigned short* ab = mat ? hin : aggin;
        size_t ko = (size_t)kt * 32 + quad * 8;
        short8 a0 = *(const short8*)(ab + (size_t)ra0 * HH + ko);
        short8 a1 = *(const short8*)(ab + (size_t)ra1 * HH + ko);
#pragma unroll
        for (int g = 0; g < 3; ++g) {
            int ct = g * 8 + w8;
            short8 bf = *(const short8*)(db + ct * 512 + lane * 8);
            if (mat == 0) {
                gi[0][g] = __builtin_amdgcn_mfma_f32_16x16x32_bf16(a0, bf, gi[0][g], 0, 0, 0);
                gi[1][g] = __builtin_amdgcn_mfma_f32_16x16x32_bf16(a1, bf, gi[1][g], 0, 0, 0);
            } else {
                gh[0][g] = __builtin_amdgcn_mfma_f32_16x16x32_bf16(a0, bf, gh[0][g], 0, 0, 0);
                gh[1][g] = __builtin_amdgcn_mfma_f32_16x16x32_bf16(a1, bf, gh[1][g], 0, 0, 0);
            }
        }
        __syncthreads();  // compute-s reads done before next iter's ds_write
    }

    // epilogue: last slice read Bb[1]; Bb[0] reads ended before the final barrier -> reuse as staging
    unsigned short* stg = Bb[0];
    {
        int c = w8 * 16 + l15;
        float bir = b_ih[c], biz = b_ih[128 + c], bin_ = b_ih[256 + c];
        float bhr = b_hh[c], bhz = b_hh[128 + c], bhn = b_hh[256 + c];
#pragma unroll
        for (int m = 0; m < 2; ++m) {
#pragma unroll
            for (int j = 0; j < 4; ++j) {
                int row = mg * 32 + m * 16 + quad * 4 + j;
                int gr = min(M0 + row, n - 1);
                float hp = 0.0f;
                if (!HALF || w8 < 4) hp = bfs(hin[(size_t)gr * HH + c]);
                float gir = gi[m][0][j] + bir;
                float ghr = gh[m][0][j] + bhr;
                float giz = gi[m][1][j] + biz;
                float ghz = gh[m][1][j] + bhz;
                float gin = gi[m][2][j] + bin_;
                float ghn = gh[m][2][j] + bhn;
                float rr = sigmf(gir + ghr);
                float zz = sigmf(giz + ghz);
                float nn = tanhfast(gin + rr * ghn);
                stg[row * LPAD_US + c] = f2bf((1.0f - zz) * nn + zz * hp);
            }
        }
    }
    __syncthreads();

    // coalesced store of h_new: 1024 threads x 1 uint4 (64 rows x 16 uint4)
    {
        int row = tid >> 4;
        int q = tid & 15;
        int gr = M0 + row;
        if (gr < n) {
            uint4 v = *(const uint4*)(stg + row * LPAD_US + q * 8);
            *(uint4*)(hout + (size_t)gr * HH + q * 8) = v;
        }
    }
}

// Pack whh^T into MFMA B-fragment order.
__global__ void pack_whh(const float* __restrict__ w_hh, unsigned short* __restrict__ whhp) {
    int id = blockIdx.x * blockDim.x + threadIdx.x;
    if (id >= 4 * 24 * 64 * 8) return;
    int j = id & 7;
    int lane = (id >> 3) & 63;
    int ctkt = id >> 9;
    int ct = ctkt % 24;
    int kt = ctkt / 24;
    int k = kt * 32 + (lane >> 4) * 8 + j;
    int col = ct * 16 + (lane & 15);
    whhp[id] = f2bf(w_hh[col * HH + k]);
}

// Wf[l] = ggc[l] @ w_ih^T, packed in MFMA B-fragment order (bf16).
__global__ void pack_wf(const float* __restrict__ ggc, const float* __restrict__ w_ih,
                        unsigned short* __restrict__ Wfp) {
    int id = blockIdx.x * blockDim.x + threadIdx.x;
    if (id >= LAYERS * 4 * 24 * 64 * 8) return;
    int l = id / 49152;
    int rem = id % 49152;
    int j = rem & 7;
    int lane = (rem >> 3) & 63;
    int ctkt = rem >> 9;
    int ct = ctkt % 24;
    int kt = ctkt / 24;
    int k = kt * 32 + (lane >> 4) * 8 + j;
    int col = ct * 16 + (lane & 15);
    const float4* gr = (const float4*)(ggc + ((size_t)l * HH + k) * HH);
    const float4* wr = (const float4*)(w_ih + (size_t)col * HH);
    float acc = 0.0f;
#pragma unroll 4
    for (int q = 0; q < HH / 4; ++q) {
        float4 g = gr[q], w = wr[q];
        acc += g.x * w.x + g.y * w.y + g.z * w.z + g.w * w.w;
    }
    Wfp[id] = f2bf(acc);
}

// Per-node mu/sigma from bf16 h. One wave per node, lane = 2 channels.
__global__ void readout_kernel(const unsigned int* __restrict__ h2, const float* __restrict__ w1,
                               const float* __restrict__ b1, const float* __restrict__ w2,
                               const float* __restrict__ b2,
                               float* __restrict__ out_mu, float* __restrict__ out_sg, int n) {
    int wave = (int)((blockIdx.x * blockDim.x + threadIdx.x) >> 6);
    int lane = threadIdx.x & 63;
    if (wave >= n) return;
    unsigned int u = h2[(size_t)wave * 64 + lane];
    float x0 = fmaxf(bflo(u), 0.0f);
    float x1 = fmaxf(bfhi(u), 0.0f);
    float2 wv1 = ((const float2*)w1)[lane];
    float2 wv2 = ((const float2*)w2)[lane];
    float a1 = x0 * wv1.x + x1 * wv1.y;
    float a2 = x0 * wv2.x + x1 * wv2.y;
#pragma unroll
    for (int off = 32; off > 0; off >>= 1) {
        a1 += __shfl_down(a1, off, 64);
        a2 += __shfl_down(a2, off, 64);
    }
    if (lane == 0) {
        float mu = a1 + b1[0];
        float x2 = a2 + b2[0];
        float sg = (x2 > 20.0f) ? x2 : __logf(1.0f + __expf(x2));
        out_mu[wave] = mu;
        out_sg[wave] = sg;
    }
}

__device__ __forceinline__ int lbound(const int* __restrict__ a, int n, int v) {
    int lo = 0, hi = n;
    while (lo < hi) {
        int m = (lo + hi) >> 1;
        if (a[m] < v) lo = m + 1; else hi = m;
    }
    return lo;
}

// One block per graph: block-reduce mu_all/sigma_all, apply correction. Zero atomics.
__global__ void seg_correct_kernel(const float* __restrict__ out_mu, const float* __restrict__ out_sg,
                                   const int* __restrict__ batch, float* __restrict__ out_muc, int n) {
    int g = blockIdx.x;
    int lo = lbound(batch, n, g);
    int hi = lbound(batch, n, g + 1);
    float smu = 0.0f, ssg = 0.0f;
    for (int i = lo + threadIdx.x; i < hi; i += blockDim.x) {
        smu += out_mu[i];
        ssg += out_sg[i];
    }
#pragma unroll
    for (int off = 32; off > 0; off >>= 1) {
        smu += __shfl_down(smu, off, 64);
        ssg += __shfl_down(ssg, off, 64);
    }
    __shared__ float pm[4], ps[4];
    int wave = threadIdx.x >> 6;
    int lane = threadIdx.x & 63;
    if (lane == 0) { pm[wave] = smu; ps[wave] = ssg; }
    __syncthreads();
    float tot_mu = pm[0] + pm[1] + pm[2] + pm[3];
    float tot_sg = ps[0] + ps[1] + ps[2] + ps[3];
    for (int i = lo + threadIdx.x; i < hi; i += blockDim.x) {
        out_muc[i] = out_mu[i] - tot_mu * (out_sg[i] / tot_sg);
    }
}

extern "C" void kernel_launch(void* const* d_in, const int* in_sizes, int n_in,
                              void* d_out, int out_size, void* d_ws, size_t ws_size,
                              hipStream_t stream) {
    const float* x      = (const float*)d_in[0];
    const int*   ei     = (const int*)d_in[1];
    const int*   batch  = (const int*)d_in[2];
    const float* lin0_w = (const float*)d_in[3];
    const float* ggc    = (const float*)d_in[4];
    const float* w_ih   = (const float*)d_in[5];
    const float* w_hh   = (const float*)d_in[6];
    const float* b_ih   = (const float*)d_in[7];
    const float* b_hh   = (const float*)d_in[8];
    const float* l1w    = (const float*)d_in[9];
    const float* l1b    = (const float*)d_in[10];
    const float* l2w    = (const float*)d_in[11];
    const float* l2b    = (const float*)d_in[12];

    int n = in_sizes[0] / FIN;   // 100000
    int e = in_sizes[1] / 2;     // 1600000
    const int* src = ei;
    const int* dstp = ei + e;

    float* out = (float*)d_out;
    float* out_muc = out;                              // [n]
    float* out_x1  = out + n;                          // [n*64]
    float* out_sg  = out + n + (size_t)n * EMB;        // [n]
    float* out_mu  = out_sg + n;                       // [n]

    // workspace layout (all 16B aligned)
    unsigned short* hbf0 = (unsigned short*)d_ws;                      // n*128 bf16
    unsigned short* hbf1 = hbf0 + (size_t)n * HH;                      // n*128 bf16
    unsigned short* Wfp  = hbf1 + (size_t)n * HH;                      // 4*49152 bf16
    unsigned short* whhp = Wfp + (size_t)LAYERS * 49152;               // 49152 bf16
    int*            deg      = (int*)(whhp + 49152 + 8);               // n
    int*            rowptr   = deg + n;                                // n+1
    int*            blocksum = rowptr + n + 1;                         // 64
    int*            blockoff = blocksum + 64;                          // 64
    int*            bucket_cnt = blockoff + 64;                        // MAXNB
    int*            col      = bucket_cnt + MAXNB;                     // e
    unsigned*       ebuf     = (unsigned*)hbf1;  // MAXNB*ECAP*4 = 16.8MB, aliases hbf1
                                                 // (dead before first agg write to hbf1)

    int nbuck = (n + SPAN - 1) >> SPANSHIFT;   // 196
    hipMemsetAsync(bucket_cnt, 0, MAXNB * sizeof(int), stream);

    int wave_blocks = (n * 64 + 255) / 256;
    lin0_kernel<<<wave_blocks, 256, 0, stream>>>(x, lin0_w, out_x1, hbf0, n);

    int eb = (e + 16383) / 16384;  // 98
    bucket_scatter_direct<<<eb, 1024, 0, stream>>>(src, dstp, bucket_cnt, ebuf, e);
    deg_from_buckets<<<nbuck, 256, 0, stream>>>(ebuf, bucket_cnt, deg, n);

    int nb = (n + SCAN_CHUNK) / SCAN_CHUNK;  // covers idx==n too
    scan_partial<<<nb, 256, 0, stream>>>(deg, blocksum, n);
    scan_blocksums<<<1, 64, 0, stream>>>(blocksum, blockoff, nb);
    scan_final<<<nb, 256, 0, stream>>>(deg, blockoff, rowptr, n);

    place_kernel<<<nbuck, 256, 0, stream>>>(ebuf, bucket_cnt, rowptr, col, n);

    pack_whh<<<(49152 + 255) / 256, 256, 0, stream>>>(w_hh, whhp);
    pack_wf<<<(LAYERS * 49152 + 255) / 256, 256, 0, stream>>>(ggc, w_ih, Wfp);

    int node_wave_blocks = (n + 7) / 8;  // 512 thr = 8 waves = 8 nodes/block
    int gru_blocks = (n + TM - 1) / TM;  // 1563
    unsigned short* hin = hbf0;
    unsigned short* hother = hbf1;
    for (int l = 0; l < LAYERS; ++l) {
        if (l == 0) {
            agg_kernel<1><<<node_wave_blocks, 512, 0, stream>>>(hin, hother, rowptr, col, n);
            gru_kernel<1><<<gru_blocks, 1024, 0, stream>>>(hother, hin, hother,
                                                           Wfp, whhp, b_ih, b_hh, n);
        } else {
            agg_kernel<0><<<node_wave_blocks, 512, 0, stream>>>(hin, hother, rowptr, col, n);
            gru_kernel<0><<<gru_blocks, 1024, 0, stream>>>(hother, hin, hother,
                                                           Wfp + (size_t)l * 49152, whhp,
                                                           b_ih, b_hh, n);
        }
        unsigned short* t = hin; hin = hother; hother = t;
    }
    // LAYERS=4 (even) -> final state in hbf0 (= hin after loop)

    readout_kernel<<<wave_blocks, 256, 0, stream>>>((const unsigned int*)hin, l1w, l1b, l2w, l2b,
                                                    out_mu, out_sg, n);
    seg_correct_kernel<<<GG, 256, 0, stream>>>(out_mu, out_sg, batch, out_muc, n);
}

// Round 6
// 821.013 us; speedup vs baseline: 1.0421x; 1.0421x over previous
//
#include <hip/hip_runtime.h>
#include <math.h>

#define NN 100000
#define FIN 27
#define EMB 64
#define HH 128
#define LAYERS 4
#define GG 512
#define SCAN_CHUNK 2048   // 256 threads x 8 elements
#define SPAN 512          // nodes per bucket
#define SPANSHIFT 9
#define MAXNB 256
#define ECAP 16384        // per-bucket edge slab capacity (mean ~8163)
#define TM 64             // rows per gru M-step (4 m-tiles of 16)

typedef __attribute__((ext_vector_type(8))) short short8;
typedef __attribute__((ext_vector_type(4))) float floatx4;

__device__ __forceinline__ float sigmf(float x) { return 1.0f / (1.0f + __expf(-x)); }
__device__ __forceinline__ float tanhfast(float x) { return 1.0f - 2.0f / (__expf(2.0f * x) + 1.0f); }

__device__ __forceinline__ unsigned short f2bf(float f) {
    unsigned int u = __float_as_uint(f);
    u += 0x7FFFu + ((u >> 16) & 1u);
    return (unsigned short)(u >> 16);
}

__device__ __forceinline__ float bflo(unsigned int v) { return __uint_as_float(v << 16); }
__device__ __forceinline__ float bfhi(unsigned int v) { return __uint_as_float(v & 0xFFFF0000u); }
__device__ __forceinline__ float bfs(unsigned short v) { return __uint_as_float(((unsigned)v) << 16); }

// x1 = sigmoid(x @ lin0_w) (fp32, exact output); h = x1 in bf16 (lower 64 ch only;
// upper half is never read: agg<HALF> reads 128B rows, gru<HALF> guards kt/c).
__global__ void lin0_kernel(const float* __restrict__ x, const float* __restrict__ w,
                            float* __restrict__ x1_out, unsigned short* __restrict__ hbf, int n) {
    int wave = (int)((blockIdx.x * blockDim.x + threadIdx.x) >> 6);
    int lane = threadIdx.x & 63;
    if (wave >= n) return;
    const float* xr = x + (size_t)wave * FIN;
    float acc = 0.0f;
#pragma unroll
    for (int k = 0; k < FIN; ++k) acc += xr[k] * w[k * EMB + lane];
    float v = 1.0f / (1.0f + expf(-acc));
    x1_out[(size_t)wave * EMB + lane] = v;
    hbf[(size_t)wave * HH + lane] = f2bf(v);
}

// Direct-reservation bucketed scatter: one pass over edges. Per-block LDS hist,
// one global atomic per (block,bucket), packed (dst_local<<17)|src into slab b*ECAP.
__global__ void bucket_scatter_direct(const int* __restrict__ src, const int* __restrict__ dst,
                                      int* __restrict__ bucket_cnt, unsigned* __restrict__ ebuf,
                                      int e) {
    __shared__ int lh[MAXNB];
    __shared__ int gb[MAXNB];
    int t = threadIdx.x;  // 1024
    for (int i = t; i < MAXNB; i += 1024) lh[i] = 0;
    __syncthreads();
    int base = blockIdx.x * 16384;
    int lidx[16], sv[16], dv[16];
#pragma unroll
    for (int i = 0; i < 16; ++i) {
        int eid = base + i * 1024 + t;
        if (eid < e) {
            sv[i] = src[eid];
            dv[i] = dst[eid];
            lidx[i] = atomicAdd(&lh[dv[i] >> SPANSHIFT], 1);
        } else lidx[i] = -1;
    }
    __syncthreads();
    for (int i = t; i < MAXNB; i += 1024) {
        int c = lh[i];
        gb[i] = c ? atomicAdd(&bucket_cnt[i], c) : 0;
    }
    __syncthreads();
#pragma unroll
    for (int i = 0; i < 16; ++i) {
        if (lidx[i] >= 0) {
            int b = dv[i] >> SPANSHIFT;
            int pos = gb[b] + lidx[i];
            if (pos < ECAP) {
                unsigned dl = (unsigned)(dv[i] - (b << SPANSHIFT));
                ebuf[(size_t)b * ECAP + pos] = (dl << 17) | (unsigned)sv[i];
            }
        }
    }
}

// Per-node degree via per-bucket LDS histogram.
__global__ void deg_from_buckets(const unsigned* __restrict__ ebuf, const int* __restrict__ bucket_cnt,
                                 int* __restrict__ deg, int n) {
    __shared__ int ld[SPAN];
    int b = blockIdx.x, t = threadIdx.x;  // 256
    ld[t] = 0; ld[t + 256] = 0;
    __syncthreads();
    int cnt = bucket_cnt[b];
    if (cnt > ECAP) cnt = ECAP;
    size_t base = (size_t)b * ECAP;
    int nodebase = b << SPANSHIFT;
    for (int j = t; j < cnt; j += 256)
        atomicAdd(&ld[ebuf[base + j] >> 17], 1);
    __syncthreads();
    int i0 = nodebase + t, i1 = nodebase + 256 + t;
    if (i0 < n) deg[i0] = ld[t];
    if (i1 < n) deg[i1] = ld[t + 256];
}

// ---- multi-block exclusive scan of deg -> rowptr ----
__global__ void scan_partial(const int* __restrict__ deg, int* __restrict__ blocksum, int n) {
    int b = blockIdx.x, t = threadIdx.x;
    int base = b * SCAN_CHUNK + t * 8;
    int s = 0;
#pragma unroll
    for (int i = 0; i < 8; ++i) {
        int idx = base + i;
        if (idx < n) s += deg[idx];
    }
#pragma unroll
    for (int off = 32; off > 0; off >>= 1) s += __shfl_down(s, off, 64);
    __shared__ int ws[4];
    if ((t & 63) == 0) ws[t >> 6] = s;
    __syncthreads();
    if (t == 0) blocksum[b] = ws[0] + ws[1] + ws[2] + ws[3];
}

__global__ void scan_blocksums(const int* __restrict__ blocksum, int* __restrict__ blockoff, int nb) {
    int t = threadIdx.x;
    int own = (t < nb) ? blocksum[t] : 0;
    int v = own;
    for (int off = 1; off < 64; off <<= 1) {
        int u = __shfl_up(v, off, 64);
        if (t >= off) v += u;
    }
    if (t < nb) blockoff[t] = v - own;
}

__global__ void scan_final(const int* __restrict__ deg, const int* __restrict__ blockoff,
                           int* __restrict__ rowptr, int n) {
    int b = blockIdx.x, t = threadIdx.x;
    int base = b * SCAN_CHUNK + t * 8;
    int v[8];
    int s = 0;
#pragma unroll
    for (int i = 0; i < 8; ++i) {
        int idx = base + i;
        v[i] = (idx < n) ? deg[idx] : 0;
        s += v[i];
    }
    __shared__ int ts[256];
    ts[t] = s;
    __syncthreads();
    for (int off = 1; off < 256; off <<= 1) {
        int u = (t >= off) ? ts[t - off] : 0;
        __syncthreads();
        ts[t] += u;
        __syncthreads();
    }
    int run = blockoff[b] + ((t == 0) ? 0 : ts[t - 1]);
#pragma unroll
    for (int i = 0; i < 8; ++i) {
        int idx = base + i;
        if (idx < n) {
            rowptr[idx] = run;
            run += v[i];
        } else if (idx == n) {
            rowptr[n] = run;
        }
    }
}

// Place edges into CSR col with LDS cursors; writes confined to ~32KB/bucket.
__global__ void place_kernel(const unsigned* __restrict__ ebuf, const int* __restrict__ bucket_cnt,
                             const int* __restrict__ rowptr, int* __restrict__ col, int n) {
    __shared__ int cur[SPAN];
    int b = blockIdx.x, t = threadIdx.x;  // 256
    int nodebase = b << SPANSHIFT;
    int i0 = nodebase + t, i1 = nodebase + 256 + t;
    cur[t] = (i0 < n) ? rowptr[i0] : 0;
    cur[t + 256] = (i1 < n) ? rowptr[i1] : 0;
    __syncthreads();
    int cnt = bucket_cnt[b];
    if (cnt > ECAP) cnt = ECAP;
    size_t base = (size_t)b * ECAP;
    for (int j = t; j < cnt; j += 256) {
        unsigned ed = ebuf[base + j];
        int pos = atomicAdd(&cur[ed >> 17], 1);
        col[pos] = (int)(ed & 0x1FFFFu);
    }
}

// Pure gather-aggregate: one wave per node, agg row written bf16 to aggout.
// HALF=1: h rows have upper 64 ch == 0 -> read only 128B/row via uint2.
// At the L3->L2 random-fill ceiling (~2.9-3.4 TB/s; FETCH = 8 XCD x h-size replication).
template <int HALF>
__global__ __launch_bounds__(512, 8)
void agg_kernel(const unsigned short* __restrict__ hin, unsigned short* __restrict__ aggout,
                const int* __restrict__ rowptr, const int* __restrict__ col, int n) {
    int node = (int)((blockIdx.x * blockDim.x + threadIdx.x) >> 6);
    int lane = threadIdx.x & 63;
    if (node >= n) return;
    int l16 = lane & 15;
    int lg = lane >> 4;
    const uint4* hin4 = (const uint4*)hin;
    const uint2* hin2 = (const uint2*)hin;
    int r0 = rowptr[node];
    int r1 = rowptr[node + 1];

    if (HALF) {
        float a[4], b[4];
#pragma unroll
        for (int k = 0; k < 4; ++k) { a[k] = 0.0f; b[k] = 0.0f; }
        int j = r0 + lg;
        for (; j + 4 < r1; j += 8) {
            int s0 = col[j], s1 = col[j + 4];
            uint2 v0 = hin2[(size_t)s0 * 32 + l16];
            uint2 v1 = hin2[(size_t)s1 * 32 + l16];
            a[0] += bflo(v0.x); a[1] += bfhi(v0.x);
            a[2] += bflo(v0.y); a[3] += bfhi(v0.y);
            b[0] += bflo(v1.x); b[1] += bfhi(v1.x);
            b[2] += bflo(v1.y); b[3] += bfhi(v1.y);
        }
        for (; j < r1; j += 4) {
            int s = col[j];
            uint2 v = hin2[(size_t)s * 32 + l16];
            a[0] += bflo(v.x); a[1] += bfhi(v.x);
            a[2] += bflo(v.y); a[3] += bfhi(v.y);
        }
#pragma unroll
        for (int k = 0; k < 4; ++k) {
            a[k] += b[k];
            a[k] += __shfl_xor(a[k], 32, 64);
            a[k] += __shfl_xor(a[k], 16, 64);
        }
        if (lg == 0) {
            uint2 o;
            o.x = (unsigned)f2bf(a[0]) | ((unsigned)f2bf(a[1]) << 16);
            o.y = (unsigned)f2bf(a[2]) | ((unsigned)f2bf(a[3]) << 16);
            *(uint2*)(aggout + (size_t)node * HH + l16 * 4) = o;
        }
    } else {
        float a[8], b[8];
#pragma unroll
        for (int k = 0; k < 8; ++k) { a[k] = 0.0f; b[k] = 0.0f; }
        int j = r0 + lg;
        for (; j + 12 < r1; j += 16) {
            int s0 = col[j], s1 = col[j + 4], s2 = col[j + 8], s3 = col[j + 12];
            uint4 v0 = hin4[(size_t)s0 * 16 + l16];
            uint4 v1 = hin4[(size_t)s1 * 16 + l16];
            uint4 v2 = hin4[(size_t)s2 * 16 + l16];
            uint4 v3 = hin4[(size_t)s3 * 16 + l16];
            a[0] += bflo(v0.x); a[1] += bfhi(v0.x);
            a[2] += bflo(v0.y); a[3] += bfhi(v0.y);
            a[4] += bflo(v0.z); a[5] += bfhi(v0.z);
            a[6] += bflo(v0.w); a[7] += bfhi(v0.w);
            b[0] += bflo(v1.x); b[1] += bfhi(v1.x);
            b[2] += bflo(v1.y); b[3] += bfhi(v1.y);
            b[4] += bflo(v1.z); b[5] += bfhi(v1.z);
            b[6] += bflo(v1.w); b[7] += bfhi(v1.w);
            a[0] += bflo(v2.x); a[1] += bfhi(v2.x);
            a[2] += bflo(v2.y); a[3] += bfhi(v2.y);
            a[4] += bflo(v2.z); a[5] += bfhi(v2.z);
            a[6] += bflo(v2.w); a[7] += bfhi(v2.w);
            b[0] += bflo(v3.x); b[1] += bfhi(v3.x);
            b[2] += bflo(v3.y); b[3] += bfhi(v3.y);
            b[4] += bflo(v3.z); b[5] += bfhi(v3.z);
            b[6] += bflo(v3.w); b[7] += bfhi(v3.w);
        }
        for (; j + 4 < r1; j += 8) {
            int s0 = col[j], s1 = col[j + 4];
            uint4 v0 = hin4[(size_t)s0 * 16 + l16];
            uint4 v1 = hin4[(size_t)s1 * 16 + l16];
            a[0] += bflo(v0.x); a[1] += bfhi(v0.x);
            a[2] += bflo(v0.y); a[3] += bfhi(v0.y);
            a[4] += bflo(v0.z); a[5] += bfhi(v0.z);
            a[6] += bflo(v0.w); a[7] += bfhi(v0.w);
            b[0] += bflo(v1.x); b[1] += bfhi(v1.x);
            b[2] += bflo(v1.y); b[3] += bfhi(v1.y);
            b[4] += bflo(v1.z); b[5] += bfhi(v1.z);
            b[6] += bflo(v1.w); b[7] += bfhi(v1.w);
        }
        for (; j < r1; j += 4) {
            int s = col[j];
            uint4 v = hin4[(size_t)s * 16 + l16];
            a[0] += bflo(v.x); a[1] += bfhi(v.x);
            a[2] += bflo(v.y); a[3] += bfhi(v.y);
            a[4] += bflo(v.z); a[5] += bfhi(v.z);
            a[6] += bflo(v.w); a[7] += bfhi(v.w);
        }
#pragma unroll
        for (int k = 0; k < 8; ++k) {
            a[k] += b[k];
            a[k] += __shfl_xor(a[k], 32, 64);
            a[k] += __shfl_xor(a[k], 16, 64);
        }
        if (lg == 0) {
            uint4 o;
            o.x = (unsigned)f2bf(a[0]) | ((unsigned)f2bf(a[1]) << 16);
            o.y = (unsigned)f2bf(a[2]) | ((unsigned)f2bf(a[3]) << 16);
            o.z = (unsigned)f2bf(a[4]) | ((unsigned)f2bf(a[5]) << 16);
            o.w = (unsigned)f2bf(a[6]) | ((unsigned)f2bf(a[7]) << 16);
            *(uint4*)(aggout + (size_t)node * HH + l16 * 8) = o;
        }
    }
}

// Persistent GEMM + GRU epilogue. KEY CHANGE vs R1-R5:
// R1-R3 (per-wave B streams from L2): pinned ~60-66us (per-CU TA/L1 VMEM path).
// R4 (LDS-staged B, 16 barriers/block): 117us (serialized latency, nothing overlaps).
// Here: B lives in REGISTERS for the kernel's lifetime. B/layer = 192KB; a wave
// owning ct-group w8 needs 3ct x 4kt x 2mat = 24 fragments = 96 VGPR. Loaded ONCE
// (24 wave-VMEM), then a grid-stride persistent loop over M: zero B memory traffic,
// zero staging, one barrier per step (in-place agg->h_new hazard). 8 waves/block,
// 2/SIMD (launch_bounds(512,2) -> 256-reg budget; ~130 VGPR + 96 acc-AGPR).
// A-fragments read direct from global (64 rows shared by 8 waves -> L1-hot).
template <int HALF>
__global__ __launch_bounds__(512, 2)
void gru_kernel(const unsigned short* __restrict__ aggin,
                const unsigned short* __restrict__ hin,
                unsigned short* __restrict__ hout,
                const unsigned short* __restrict__ Wfp,
                const unsigned short* __restrict__ whhp,
                const float* __restrict__ b_ih, const float* __restrict__ b_hh,
                int n, int nsteps) {
    int wave = threadIdx.x >> 6;   // 0..7 = ct group
    int lane = threadIdx.x & 63;
    int quad = lane >> 4;
    int l15 = lane & 15;
    const int KTMAX = HALF ? 2 : 4;

    // B fragments in registers (filled once; kt >= KTMAX slots DCE'd)
    short8 Bi[3][4], Bh[3][4];
#pragma unroll
    for (int g = 0; g < 3; ++g) {
#pragma unroll
        for (int kt = 0; kt < 4; ++kt) {
            if (kt < KTMAX) {
                int ct = g * 8 + wave;
                size_t boff = ((size_t)(kt * 24 + ct) * 64 + lane) * 8;
                Bi[g][kt] = *(const short8*)(Wfp + boff);
                Bh[g][kt] = *(const short8*)(whhp + boff);
            }
        }
    }

    // epilogue channel + bias scalars (uniform per thread for the whole kernel)
    int c = wave * 16 + l15;
    float bir = b_ih[c], biz = b_ih[128 + c], bin_ = b_ih[256 + c];
    float bhr = b_hh[c], bhz = b_hh[128 + c], bhn = b_hh[256 + c];

    for (int step = blockIdx.x; step < nsteps; step += gridDim.x) {
        int M0 = step * TM;

        floatx4 gi[4][3], gh[4][3];
#pragma unroll
        for (int m = 0; m < 4; ++m)
#pragma unroll
            for (int g = 0; g < 3; ++g) {
                gi[m][g] = (floatx4)0.0f;
                gh[m][g] = (floatx4)0.0f;
            }

        int rowA[4];
#pragma unroll
        for (int m = 0; m < 4; ++m) rowA[m] = min(M0 + m * 16 + l15, n - 1);

#pragma unroll
        for (int kt = 0; kt < 4; ++kt) {
            if (kt < KTMAX) {
                size_t ko = (size_t)kt * 32 + quad * 8;
#pragma unroll
                for (int m = 0; m < 4; ++m) {
                    short8 aA = *(const short8*)(aggin + (size_t)rowA[m] * HH + ko);
                    short8 aH = *(const short8*)(hin + (size_t)rowA[m] * HH + ko);
#pragma unroll
                    for (int g = 0; g < 3; ++g) {
                        gi[m][g] = __builtin_amdgcn_mfma_f32_16x16x32_bf16(aA, Bi[g][kt], gi[m][g], 0, 0, 0);
                        gh[m][g] = __builtin_amdgcn_mfma_f32_16x16x32_bf16(aH, Bh[g][kt], gh[m][g], 0, 0, 0);
                    }
                }
            }
        }

        // hout aliases aggin (in-place per layer): all waves must finish reading
        // this step's agg rows before any wave's epilogue overwrites them.
        __syncthreads();

#pragma unroll
        for (int m = 0; m < 4; ++m) {
#pragma unroll
            for (int j = 0; j < 4; ++j) {
                int row = M0 + m * 16 + quad * 4 + j;
                if (row < n) {
                    float hp = 0.0f;
                    if (!HALF || c < 64) hp = bfs(hin[(size_t)row * HH + c]);
                    float gir = gi[m][0][j] + bir;
                    float ghr = gh[m][0][j] + bhr;
                    float giz = gi[m][1][j] + biz;
                    float ghz = gh[m][1][j] + bhz;
                    float gin = gi[m][2][j] + bin_;
                    float ghn = gh[m][2][j] + bhn;
                    float rr = sigmf(gir + ghr);
                    float zz = sigmf(giz + ghz);
                    float nnv = tanhfast(gin + rr * ghn);
                    hout[(size_t)row * HH + c] = f2bf((1.0f - zz) * nnv + zz * hp);
                }
            }
        }
    }
}

// Pack whh^T into MFMA B-fragment order.
__global__ void pack_whh(const float* __restrict__ w_hh, unsigned short* __restrict__ whhp) {
    int id = blockIdx.x * blockDim.x + threadIdx.x;
    if (id >= 4 * 24 * 64 * 8) return;
    int j = id & 7;
    int lane = (id >> 3) & 63;
    int ctkt = id >> 9;
    int ct = ctkt % 24;
    int kt = ctkt / 24;
    int k = kt * 32 + (lane >> 4) * 8 + j;
    int col = ct * 16 + (lane & 15);
    whhp[id] = f2bf(w_hh[col * HH + k]);
}

// Wf[l] = ggc[l] @ w_ih^T, packed in MFMA B-fragment order (bf16).
__global__ void pack_wf(const float* __restrict__ ggc, const float* __restrict__ w_ih,
                        unsigned short* __restrict__ Wfp) {
    int id = blockIdx.x * blockDim.x + threadIdx.x;
    if (id >= LAYERS * 4 * 24 * 64 * 8) return;
    int l = id / 49152;
    int rem = id % 49152;
    int j = rem & 7;
    int lane = (rem >> 3) & 63;
    int ctkt = rem >> 9;
    int ct = ctkt % 24;
    int kt = ctkt / 24;
    int k = kt * 32 + (lane >> 4) * 8 + j;
    int col = ct * 16 + (lane & 15);
    const float4* gr = (const float4*)(ggc + ((size_t)l * HH + k) * HH);
    const float4* wr = (const float4*)(w_ih + (size_t)col * HH);
    float acc = 0.0f;
#pragma unroll 4
    for (int q = 0; q < HH / 4; ++q) {
        float4 g = gr[q], w = wr[q];
        acc += g.x * w.x + g.y * w.y + g.z * w.z + g.w * w.w;
    }
    Wfp[id] = f2bf(acc);
}

// Per-node mu/sigma from bf16 h. One wave per node, lane = 2 channels.
__global__ void readout_kernel(const unsigned int* __restrict__ h2, const float* __restrict__ w1,
                               const float* __restrict__ b1, const float* __restrict__ w2,
                               const float* __restrict__ b2,
                               float* __restrict__ out_mu, float* __restrict__ out_sg, int n) {
    int wave = (int)((blockIdx.x * blockDim.x + threadIdx.x) >> 6);
    int lane = threadIdx.x & 63;
    if (wave >= n) return;
    unsigned int u = h2[(size_t)wave * 64 + lane];
    float x0 = fmaxf(bflo(u), 0.0f);
    float x1 = fmaxf(bfhi(u), 0.0f);
    float2 wv1 = ((const float2*)w1)[lane];
    float2 wv2 = ((const float2*)w2)[lane];
    float a1 = x0 * wv1.x + x1 * wv1.y;
    float a2 = x0 * wv2.x + x1 * wv2.y;
#pragma unroll
    for (int off = 32; off > 0; off >>= 1) {
        a1 += __shfl_down(a1, off, 64);
        a2 += __shfl_down(a2, off, 64);
    }
    if (lane == 0) {
        float mu = a1 + b1[0];
        float x2 = a2 + b2[0];
        float sg = (x2 > 20.0f) ? x2 : __logf(1.0f + __expf(x2));
        out_mu[wave] = mu;
        out_sg[wave] = sg;
    }
}

__device__ __forceinline__ int lbound(const int* __restrict__ a, int n, int v) {
    int lo = 0, hi = n;
    while (lo < hi) {
        int m = (lo + hi) >> 1;
        if (a[m] < v) lo = m + 1; else hi = m;
    }
    return lo;
}

// One block per graph: block-reduce mu_all/sigma_all, apply correction. Zero atomics.
__global__ void seg_correct_kernel(const float* __restrict__ out_mu, const float* __restrict__ out_sg,
                                   const int* __restrict__ batch, float* __restrict__ out_muc, int n) {
    int g = blockIdx.x;
    int lo = lbound(batch, n, g);
    int hi = lbound(batch, n, g + 1);
    float smu = 0.0f, ssg = 0.0f;
    for (int i = lo + threadIdx.x; i < hi; i += blockDim.x) {
        smu += out_mu[i];
        ssg += out_sg[i];
    }
#pragma unroll
    for (int off = 32; off > 0; off >>= 1) {
        smu += __shfl_down(smu, off, 64);
        ssg += __shfl_down(ssg, off, 64);
    }
    __shared__ float pm[4], ps[4];
    int wave = threadIdx.x >> 6;
    int lane = threadIdx.x & 63;
    if (lane == 0) { pm[wave] = smu; ps[wave] = ssg; }
    __syncthreads();
    float tot_mu = pm[0] + pm[1] + pm[2] + pm[3];
    float tot_sg = ps[0] + ps[1] + ps[2] + ps[3];
    for (int i = lo + threadIdx.x; i < hi; i += blockDim.x) {
        out_muc[i] = out_mu[i] - tot_mu * (out_sg[i] / tot_sg);
    }
}

extern "C" void kernel_launch(void* const* d_in, const int* in_sizes, int n_in,
                              void* d_out, int out_size, void* d_ws, size_t ws_size,
                              hipStream_t stream) {
    const float* x      = (const float*)d_in[0];
    const int*   ei     = (const int*)d_in[1];
    const int*   batch  = (const int*)d_in[2];
    const float* lin0_w = (const float*)d_in[3];
    const float* ggc    = (const float*)d_in[4];
    const float* w_ih   = (const float*)d_in[5];
    const float* w_hh   = (const float*)d_in[6];
    const float* b_ih   = (const float*)d_in[7];
    const float* b_hh   = (const float*)d_in[8];
    const float* l1w    = (const float*)d_in[9];
    const float* l1b    = (const float*)d_in[10];
    const float* l2w    = (const float*)d_in[11];
    const float* l2b    = (const float*)d_in[12];

    int n = in_sizes[0] / FIN;   // 100000
    int e = in_sizes[1] / 2;     // 1600000
    const int* src = ei;
    const int* dstp = ei + e;

    float* out = (float*)d_out;
    float* out_muc = out;                              // [n]
    float* out_x1  = out + n;                          // [n*64]
    float* out_sg  = out + n + (size_t)n * EMB;        // [n]
    float* out_mu  = out_sg + n;                       // [n]

    // workspace layout (all 16B aligned)
    unsigned short* hbf0 = (unsigned short*)d_ws;                      // n*128 bf16
    unsigned short* hbf1 = hbf0 + (size_t)n * HH;                      // n*128 bf16
    unsigned short* Wfp  = hbf1 + (size_t)n * HH;                      // 4*49152 bf16
    unsigned short* whhp = Wfp + (size_t)LAYERS * 49152;               // 49152 bf16
    int*            deg      = (int*)(whhp + 49152 + 8);               // n
    int*            rowptr   = deg + n;                                // n+1
    int*            blocksum = rowptr + n + 1;                         // 64
    int*            blockoff = blocksum + 64;                          // 64
    int*            bucket_cnt = blockoff + 64;                        // MAXNB
    int*            col      = bucket_cnt + MAXNB;                     // e
    unsigned*       ebuf     = (unsigned*)hbf1;  // MAXNB*ECAP*4 = 16.8MB, aliases hbf1
                                                 // (dead before first agg write to hbf1)

    int nbuck = (n + SPAN - 1) >> SPANSHIFT;   // 196
    hipMemsetAsync(bucket_cnt, 0, MAXNB * sizeof(int), stream);

    int wave_blocks = (n * 64 + 255) / 256;
    lin0_kernel<<<wave_blocks, 256, 0, stream>>>(x, lin0_w, out_x1, hbf0, n);

    int eb = (e + 16383) / 16384;  // 98
    bucket_scatter_direct<<<eb, 1024, 0, stream>>>(src, dstp, bucket_cnt, ebuf, e);
    deg_from_buckets<<<nbuck, 256, 0, stream>>>(ebuf, bucket_cnt, deg, n);

    int nb = (n + SCAN_CHUNK) / SCAN_CHUNK;  // covers idx==n too
    scan_partial<<<nb, 256, 0, stream>>>(deg, blocksum, n);
    scan_blocksums<<<1, 64, 0, stream>>>(blocksum, blockoff, nb);
    scan_final<<<nb, 256, 0, stream>>>(deg, blockoff, rowptr, n);

    place_kernel<<<nbuck, 256, 0, stream>>>(ebuf, bucket_cnt, rowptr, col, n);

    pack_whh<<<(49152 + 255) / 256, 256, 0, stream>>>(w_hh, whhp);
    pack_wf<<<(LAYERS * 49152 + 255) / 256, 256, 0, stream>>>(ggc, w_ih, Wfp);

    int node_wave_blocks = (n + 7) / 8;  // 512 thr = 8 waves = 8 nodes/block
    int nsteps = (n + TM - 1) / TM;      // 1563
    unsigned short* hin = hbf0;
    unsigned short* hother = hbf1;
    for (int l = 0; l < LAYERS; ++l) {
        if (l == 0) {
            agg_kernel<1><<<node_wave_blocks, 512, 0, stream>>>(hin, hother, rowptr, col, n);
            gru_kernel<1><<<256, 512, 0, stream>>>(hother, hin, hother,
                                                   Wfp, whhp, b_ih, b_hh, n, nsteps);
        } else {
            agg_kernel<0><<<node_wave_blocks, 512, 0, stream>>>(hin, hother, rowptr, col, n);
            gru_kernel<0><<<256, 512, 0, stream>>>(hother, hin, hother,
                                                   Wfp + (size_t)l * 49152, whhp,
                                                   b_ih, b_hh, n, nsteps);
        }
        unsigned short* t = hin; hin = hother; hother = t;
    }
    // LAYERS=4 (even) -> final state in hbf0 (= hin after loop)

    readout_kernel<<<wave_blocks, 256, 0, stream>>>((const unsigned int*)hin, l1w, l1b, l2w, l2b,
                                                    out_mu, out_sg, n);
    seg_correct_kernel<<<GG, 256, 0, stream>>>(out_mu, out_sg, batch, out_muc, n);
}

// Round 7
// 808.438 us; speedup vs baseline: 1.0583x; 1.0156x over previous
//
#include <hip/hip_runtime.h>
#include <math.h>

#define NN 100000
#define FIN 27
#define EMB 64
#define HH 128
#define LAYERS 4
#define GG 512
#define SCAN_CHUNK 2048   // 256 threads x 8 elements
#define SPAN 512          // nodes per bucket
#define SPANSHIFT 9
#define MAXNB 256
#define ECAP 16384        // per-bucket edge slab capacity (mean ~8163)
#define LPAD_US 136       // LDS row stride in ushorts: 272B, 16B-aligned rows
#define TMG 32            // rows per gru block
#define KCH 4             // pipeline chunks per layer

typedef __attribute__((ext_vector_type(8))) short short8;
typedef __attribute__((ext_vector_type(4))) float floatx4;

__device__ __forceinline__ float sigmf(float x) { return 1.0f / (1.0f + __expf(-x)); }
__device__ __forceinline__ float tanhfast(float x) { return 1.0f - 2.0f / (__expf(2.0f * x) + 1.0f); }

__device__ __forceinline__ unsigned short f2bf(float f) {
    unsigned int u = __float_as_uint(f);
    u += 0x7FFFu + ((u >> 16) & 1u);
    return (unsigned short)(u >> 16);
}

__device__ __forceinline__ float bflo(unsigned int v) { return __uint_as_float(v << 16); }
__device__ __forceinline__ float bfhi(unsigned int v) { return __uint_as_float(v & 0xFFFF0000u); }
__device__ __forceinline__ float bfs(unsigned short v) { return __uint_as_float(((unsigned)v) << 16); }

// x1 = sigmoid(x @ lin0_w) (fp32, exact output); h = x1 in bf16 (lower 64 ch only;
// upper half never read: agg<HALF> reads 128B rows, gru<HALF> stages zeros).
__global__ void lin0_kernel(const float* __restrict__ x, const float* __restrict__ w,
                            float* __restrict__ x1_out, unsigned short* __restrict__ hbf, int n) {
    int wave = (int)((blockIdx.x * blockDim.x + threadIdx.x) >> 6);
    int lane = threadIdx.x & 63;
    if (wave >= n) return;
    const float* xr = x + (size_t)wave * FIN;
    float acc = 0.0f;
#pragma unroll
    for (int k = 0; k < FIN; ++k) acc += xr[k] * w[k * EMB + lane];
    float v = 1.0f / (1.0f + expf(-acc));
    x1_out[(size_t)wave * EMB + lane] = v;
    hbf[(size_t)wave * HH + lane] = f2bf(v);
}

// Direct-reservation bucketed scatter: one pass over edges. Per-block LDS hist,
// one global atomic per (block,bucket), packed (dst_local<<17)|src into slab b*ECAP.
__global__ void bucket_scatter_direct(const int* __restrict__ src, const int* __restrict__ dst,
                                      int* __restrict__ bucket_cnt, unsigned* __restrict__ ebuf,
                                      int e) {
    __shared__ int lh[MAXNB];
    __shared__ int gb[MAXNB];
    int t = threadIdx.x;  // 1024
    for (int i = t; i < MAXNB; i += 1024) lh[i] = 0;
    __syncthreads();
    int base = blockIdx.x * 16384;
    int lidx[16], sv[16], dv[16];
#pragma unroll
    for (int i = 0; i < 16; ++i) {
        int eid = base + i * 1024 + t;
        if (eid < e) {
            sv[i] = src[eid];
            dv[i] = dst[eid];
            lidx[i] = atomicAdd(&lh[dv[i] >> SPANSHIFT], 1);
        } else lidx[i] = -1;
    }
    __syncthreads();
    for (int i = t; i < MAXNB; i += 1024) {
        int c = lh[i];
        gb[i] = c ? atomicAdd(&bucket_cnt[i], c) : 0;
    }
    __syncthreads();
#pragma unroll
    for (int i = 0; i < 16; ++i) {
        if (lidx[i] >= 0) {
            int b = dv[i] >> SPANSHIFT;
            int pos = gb[b] + lidx[i];
            if (pos < ECAP) {
                unsigned dl = (unsigned)(dv[i] - (b << SPANSHIFT));
                ebuf[(size_t)b * ECAP + pos] = (dl << 17) | (unsigned)sv[i];
            }
        }
    }
}

// Per-node degree via per-bucket LDS histogram.
__global__ void deg_from_buckets(const unsigned* __restrict__ ebuf, const int* __restrict__ bucket_cnt,
                                 int* __restrict__ deg, int n) {
    __shared__ int ld[SPAN];
    int b = blockIdx.x, t = threadIdx.x;  // 256
    ld[t] = 0; ld[t + 256] = 0;
    __syncthreads();
    int cnt = bucket_cnt[b];
    if (cnt > ECAP) cnt = ECAP;
    size_t base = (size_t)b * ECAP;
    int nodebase = b << SPANSHIFT;
    for (int j = t; j < cnt; j += 256)
        atomicAdd(&ld[ebuf[base + j] >> 17], 1);
    __syncthreads();
    int i0 = nodebase + t, i1 = nodebase + 256 + t;
    if (i0 < n) deg[i0] = ld[t];
    if (i1 < n) deg[i1] = ld[t + 256];
}

// ---- multi-block exclusive scan of deg -> rowptr ----
__global__ void scan_partial(const int* __restrict__ deg, int* __restrict__ blocksum, int n) {
    int b = blockIdx.x, t = threadIdx.x;
    int base = b * SCAN_CHUNK + t * 8;
    int s = 0;
#pragma unroll
    for (int i = 0; i < 8; ++i) {
        int idx = base + i;
        if (idx < n) s += deg[idx];
    }
#pragma unroll
    for (int off = 32; off > 0; off >>= 1) s += __shfl_down(s, off, 64);
    __shared__ int ws[4];
    if ((t & 63) == 0) ws[t >> 6] = s;
    __syncthreads();
    if (t == 0) blocksum[b] = ws[0] + ws[1] + ws[2] + ws[3];
}

__global__ void scan_blocksums(const int* __restrict__ blocksum, int* __restrict__ blockoff, int nb) {
    int t = threadIdx.x;
    int own = (t < nb) ? blocksum[t] : 0;
    int v = own;
    for (int off = 1; off < 64; off <<= 1) {
        int u = __shfl_up(v, off, 64);
        if (t >= off) v += u;
    }
    if (t < nb) blockoff[t] = v - own;
}

__global__ void scan_final(const int* __restrict__ deg, const int* __restrict__ blockoff,
                           int* __restrict__ rowptr, int n) {
    int b = blockIdx.x, t = threadIdx.x;
    int base = b * SCAN_CHUNK + t * 8;
    int v[8];
    int s = 0;
#pragma unroll
    for (int i = 0; i < 8; ++i) {
        int idx = base + i;
        v[i] = (idx < n) ? deg[idx] : 0;
        s += v[i];
    }
    __shared__ int ts[256];
    ts[t] = s;
    __syncthreads();
    for (int off = 1; off < 256; off <<= 1) {
        int u = (t >= off) ? ts[t - off] : 0;
        __syncthreads();
        ts[t] += u;
        __syncthreads();
    }
    int run = blockoff[b] + ((t == 0) ? 0 : ts[t - 1]);
#pragma unroll
    for (int i = 0; i < 8; ++i) {
        int idx = base + i;
        if (idx < n) {
            rowptr[idx] = run;
            run += v[i];
        } else if (idx == n) {
            rowptr[n] = run;
        }
    }
}

// Place edges into CSR col with LDS cursors; writes confined to ~32KB/bucket.
__global__ void place_kernel(const unsigned* __restrict__ ebuf, const int* __restrict__ bucket_cnt,
                             const int* __restrict__ rowptr, int* __restrict__ col, int n) {
    __shared__ int cur[SPAN];
    int b = blockIdx.x, t = threadIdx.x;  // 256
    int nodebase = b << SPANSHIFT;
    int i0 = nodebase + t, i1 = nodebase + 256 + t;
    cur[t] = (i0 < n) ? rowptr[i0] : 0;
    cur[t + 256] = (i1 < n) ? rowptr[i1] : 0;
    __syncthreads();
    int cnt = bucket_cnt[b];
    if (cnt > ECAP) cnt = ECAP;
    size_t base = (size_t)b * ECAP;
    for (int j = t; j < cnt; j += 256) {
        unsigned ed = ebuf[base + j];
        int pos = atomicAdd(&cur[ed >> 17], 1);
        col[pos] = (int)(ed & 0x1FFFFu);
    }
}

// ---- Chunk-pipelined layer kernel ----
// One dispatch runs, in the SAME grid, gru blocks for chunk k-1 (blockIdx <
// gruBlocks) and agg blocks for chunk k. The CU scheduler interleaves
// memory-bound agg waves (L3/L2 random-fill, near-zero VALU) with
// compute-bound gru waves (MFMA/VALU, low HBM) -> launch dur ~= max of the
// two, not the sum (R0 fused = sum, 117us/layer; split-serial = 61+60).
// Dependencies purely by stream order: gru(k-1) needs agg(k-1) [prev launch];
// agg(k) reads only h_l (stable this layer); gru writes h_{l+1} IN PLACE over
// its own chunk's bufA rows (nobody else reads them).
template <int HALF>
__global__ __launch_bounds__(512, 4)
void layer_chunk(const unsigned short* __restrict__ hin,   // h_l
                 unsigned short* __restrict__ bufA,        // agg out / h_{l+1} in place
                 const int* __restrict__ rowptr, const int* __restrict__ col,
                 const unsigned short* __restrict__ Wfp,
                 const unsigned short* __restrict__ whhp,
                 const float* __restrict__ b_ih, const float* __restrict__ b_hh,
                 int aggLo, int aggHi, int gruLo, int gruHi, int gruBlocks) {
    __shared__ unsigned short aggL[TMG * LPAD_US];
    __shared__ unsigned short hL[TMG * LPAD_US];

    if ((int)blockIdx.x < gruBlocks) {
        // ================= GRU part: rows [M0, M0+32) of [gruLo, gruHi) ======
        int wave = threadIdx.x >> 6;
        int lane = threadIdx.x & 63;
        int quad = lane >> 4;
        int l15 = lane & 15;
        int M0 = gruLo + (int)blockIdx.x * TMG;

        // stage agg + h rows (512 thr = 32 rows x 16 uint4)
        {
            int row = threadIdx.x >> 4;
            int q = threadIdx.x & 15;
            int gr = M0 + row;
            uint4 va = make_uint4(0, 0, 0, 0), vh = va;
            if (gr < gruHi && !(HALF && q >= 8)) {
                va = ((const uint4*)bufA)[(size_t)gr * 16 + q];
                vh = ((const uint4*)hin)[(size_t)gr * 16 + q];
            }
            *(uint4*)(&aggL[row * LPAD_US + q * 8]) = va;
            *(uint4*)(&hL[row * LPAD_US + q * 8]) = vh;
        }
        __syncthreads();

        floatx4 gi[2][3], gh[2][3];
#pragma unroll
        for (int m = 0; m < 2; ++m)
#pragma unroll
            for (int g = 0; g < 3; ++g) {
                gi[m][g] = (floatx4)0.0f;
                gh[m][g] = (floatx4)0.0f;
            }

        const int KTMAX = HALF ? 2 : 4;
#pragma unroll
        for (int kt = 0; kt < KTMAX; ++kt) {
            int kbase = kt * 32 + quad * 8;
            short8 aA0 = *(const short8*)(&aggL[l15 * LPAD_US + kbase]);
            short8 aH0 = *(const short8*)(&hL[l15 * LPAD_US + kbase]);
            short8 aA1 = *(const short8*)(&aggL[(16 + l15) * LPAD_US + kbase]);
            short8 aH1 = *(const short8*)(&hL[(16 + l15) * LPAD_US + kbase]);
#pragma unroll
            for (int g = 0; g < 3; ++g) {
                int ct = g * 8 + wave;
                size_t boff = ((size_t)(kt * 24 + ct) * 64 + lane) * 8;
                short8 bi = *(const short8*)(Wfp + boff);
                short8 bh = *(const short8*)(whhp + boff);
                gi[0][g] = __builtin_amdgcn_mfma_f32_16x16x32_bf16(aA0, bi, gi[0][g], 0, 0, 0);
                gi[1][g] = __builtin_amdgcn_mfma_f32_16x16x32_bf16(aA1, bi, gi[1][g], 0, 0, 0);
                gh[0][g] = __builtin_amdgcn_mfma_f32_16x16x32_bf16(aH0, bh, gh[0][g], 0, 0, 0);
                gh[1][g] = __builtin_amdgcn_mfma_f32_16x16x32_bf16(aH1, bh, gh[1][g], 0, 0, 0);
            }
        }

        __syncthreads();  // K-loop reads of aggL done; overwrite with h_new

        {
            int c = wave * 16 + l15;
            float bir = b_ih[c], biz = b_ih[128 + c], bin_ = b_ih[256 + c];
            float bhr = b_hh[c], bhz = b_hh[128 + c], bhn = b_hh[256 + c];
#pragma unroll
            for (int m = 0; m < 2; ++m) {
#pragma unroll
                for (int j = 0; j < 4; ++j) {
                    int row = m * 16 + quad * 4 + j;
                    int lidx = row * LPAD_US + c;
                    float gir = gi[m][0][j] + bir;
                    float ghr = gh[m][0][j] + bhr;
                    float giz = gi[m][1][j] + biz;
                    float ghz = gh[m][1][j] + bhz;
                    float gin = gi[m][2][j] + bin_;
                    float ghn = gh[m][2][j] + bhn;
                    float rr = sigmf(gir + ghr);
                    float zz = sigmf(giz + ghz);
                    float nn = tanhfast(gin + rr * ghn);
                    float hp = bfs(hL[lidx]);
                    aggL[lidx] = f2bf((1.0f - zz) * nn + zz * hp);
                }
            }
        }
        __syncthreads();

        // coalesced in-place store of h_new over bufA rows
        {
            int row = threadIdx.x >> 4;
            int q = threadIdx.x & 15;
            int gr = M0 + row;
            if (gr < gruHi) {
                uint4 v = *(const uint4*)(&aggL[row * LPAD_US + q * 8]);
                *(uint4*)(bufA + (size_t)gr * HH + q * 8) = v;
            }
        }
    } else {
        // ================= AGG part: nodes [aggLo, aggHi), one wave/node =====
        int node = aggLo + ((int)blockIdx.x - gruBlocks) * 8 + (threadIdx.x >> 6);
        int lane = threadIdx.x & 63;
        if (node >= aggHi) return;
        int l16 = lane & 15;
        int lg = lane >> 4;
        const uint4* hin4 = (const uint4*)hin;
        const uint2* hin2 = (const uint2*)hin;
        int r0 = rowptr[node];
        int r1 = rowptr[node + 1];

        if (HALF) {
            float a[4], b[4];
#pragma unroll
            for (int k = 0; k < 4; ++k) { a[k] = 0.0f; b[k] = 0.0f; }
            int j = r0 + lg;
            for (; j + 4 < r1; j += 8) {
                int s0 = col[j], s1 = col[j + 4];
                uint2 v0 = hin2[(size_t)s0 * 32 + l16];
                uint2 v1 = hin2[(size_t)s1 * 32 + l16];
                a[0] += bflo(v0.x); a[1] += bfhi(v0.x);
                a[2] += bflo(v0.y); a[3] += bfhi(v0.y);
                b[0] += bflo(v1.x); b[1] += bfhi(v1.x);
                b[2] += bflo(v1.y); b[3] += bfhi(v1.y);
            }
            for (; j < r1; j += 4) {
                int s = col[j];
                uint2 v = hin2[(size_t)s * 32 + l16];
                a[0] += bflo(v.x); a[1] += bfhi(v.x);
                a[2] += bflo(v.y); a[3] += bfhi(v.y);
            }
#pragma unroll
            for (int k = 0; k < 4; ++k) {
                a[k] += b[k];
                a[k] += __shfl_xor(a[k], 32, 64);
                a[k] += __shfl_xor(a[k], 16, 64);
            }
            if (lg == 0) {
                uint2 o;
                o.x = (unsigned)f2bf(a[0]) | ((unsigned)f2bf(a[1]) << 16);
                o.y = (unsigned)f2bf(a[2]) | ((unsigned)f2bf(a[3]) << 16);
                *(uint2*)(bufA + (size_t)node * HH + l16 * 4) = o;
            }
        } else {
            float a[8], b[8];
#pragma unroll
            for (int k = 0; k < 8; ++k) { a[k] = 0.0f; b[k] = 0.0f; }
            int j = r0 + lg;
            for (; j + 12 < r1; j += 16) {
                int s0 = col[j], s1 = col[j + 4], s2 = col[j + 8], s3 = col[j + 12];
                uint4 v0 = hin4[(size_t)s0 * 16 + l16];
                uint4 v1 = hin4[(size_t)s1 * 16 + l16];
                uint4 v2 = hin4[(size_t)s2 * 16 + l16];
                uint4 v3 = hin4[(size_t)s3 * 16 + l16];
                a[0] += bflo(v0.x); a[1] += bfhi(v0.x);
                a[2] += bflo(v0.y); a[3] += bfhi(v0.y);
                a[4] += bflo(v0.z); a[5] += bfhi(v0.z);
                a[6] += bflo(v0.w); a[7] += bfhi(v0.w);
                b[0] += bflo(v1.x); b[1] += bfhi(v1.x);
                b[2] += bflo(v1.y); b[3] += bfhi(v1.y);
                b[4] += bflo(v1.z); b[5] += bfhi(v1.z);
                b[6] += bflo(v1.w); b[7] += bfhi(v1.w);
                a[0] += bflo(v2.x); a[1] += bfhi(v2.x);
                a[2] += bflo(v2.y); a[3] += bfhi(v2.y);
                a[4] += bflo(v2.z); a[5] += bfhi(v2.z);
                a[6] += bflo(v2.w); a[7] += bfhi(v2.w);
                b[0] += bflo(v3.x); b[1] += bfhi(v3.x);
                b[2] += bflo(v3.y); b[3] += bfhi(v3.y);
                b[4] += bflo(v3.z); b[5] += bfhi(v3.z);
                b[6] += bflo(v3.w); b[7] += bfhi(v3.w);
            }
            for (; j + 4 < r1; j += 8) {
                int s0 = col[j], s1 = col[j + 4];
                uint4 v0 = hin4[(size_t)s0 * 16 + l16];
                uint4 v1 = hin4[(size_t)s1 * 16 + l16];
                a[0] += bflo(v0.x); a[1] += bfhi(v0.x);
                a[2] += bflo(v0.y); a[3] += bfhi(v0.y);
                a[4] += bflo(v0.z); a[5] += bfhi(v0.z);
                a[6] += bflo(v0.w); a[7] += bfhi(v0.w);
                b[0] += bflo(v1.x); b[1] += bfhi(v1.x);
                b[2] += bflo(v1.y); b[3] += bfhi(v1.y);
                b[4] += bflo(v1.z); b[5] += bfhi(v1.z);
                b[6] += bflo(v1.w); b[7] += bfhi(v1.w);
            }
            for (; j < r1; j += 4) {
                int s = col[j];
                uint4 v = hin4[(size_t)s * 16 + l16];
                a[0] += bflo(v.x); a[1] += bfhi(v.x);
                a[2] += bflo(v.y); a[3] += bfhi(v.y);
                a[4] += bflo(v.z); a[5] += bfhi(v.z);
                a[6] += bflo(v.w); a[7] += bfhi(v.w);
            }
#pragma unroll
            for (int k = 0; k < 8; ++k) {
                a[k] += b[k];
                a[k] += __shfl_xor(a[k], 32, 64);
                a[k] += __shfl_xor(a[k], 16, 64);
            }
            if (lg == 0) {
                uint4 o;
                o.x = (unsigned)f2bf(a[0]) | ((unsigned)f2bf(a[1]) << 16);
                o.y = (unsigned)f2bf(a[2]) | ((unsigned)f2bf(a[3]) << 16);
                o.z = (unsigned)f2bf(a[4]) | ((unsigned)f2bf(a[5]) << 16);
                o.w = (unsigned)f2bf(a[6]) | ((unsigned)f2bf(a[7]) << 16);
                *(uint4*)(bufA + (size_t)node * HH + l16 * 8) = o;
            }
        }
    }
}

// Pack whh^T into MFMA B-fragment order.
__global__ void pack_whh(const float* __restrict__ w_hh, unsigned short* __restrict__ whhp) {
    int id = blockIdx.x * blockDim.x + threadIdx.x;
    if (id >= 4 * 24 * 64 * 8) return;
    int j = id & 7;
    int lane = (id >> 3) & 63;
    int ctkt = id >> 9;
    int ct = ctkt % 24;
    int kt = ctkt / 24;
    int k = kt * 32 + (lane >> 4) * 8 + j;
    int col = ct * 16 + (lane & 15);
    whhp[id] = f2bf(w_hh[col * HH + k]);
}

// Wf[l] = ggc[l] @ w_ih^T, packed in MFMA B-fragment order (bf16).
__global__ void pack_wf(const float* __restrict__ ggc, const float* __restrict__ w_ih,
                        unsigned short* __restrict__ Wfp) {
    int id = blockIdx.x * blockDim.x + threadIdx.x;
    if (id >= LAYERS * 4 * 24 * 64 * 8) return;
    int l = id / 49152;
    int rem = id % 49152;
    int j = rem & 7;
    int lane = (rem >> 3) & 63;
    int ctkt = rem >> 9;
    int ct = ctkt % 24;
    int kt = ctkt / 24;
    int k = kt * 32 + (lane >> 4) * 8 + j;
    int col = ct * 16 + (lane & 15);
    const float4* gr = (const float4*)(ggc + ((size_t)l * HH + k) * HH);
    const float4* wr = (const float4*)(w_ih + (size_t)col * HH);
    float acc = 0.0f;
#pragma unroll 4
    for (int q = 0; q < HH / 4; ++q) {
        float4 g = gr[q], w = wr[q];
        acc += g.x * w.x + g.y * w.y + g.z * w.z + g.w * w.w;
    }
    Wfp[id] = f2bf(acc);
}

// Per-node mu/sigma from bf16 h. One wave per node, lane = 2 channels.
__global__ void readout_kernel(const unsigned int* __restrict__ h2, const float* __restrict__ w1,
                               const float* __restrict__ b1, const float* __restrict__ w2,
                               const float* __restrict__ b2,
                               float* __restrict__ out_mu, float* __restrict__ out_sg, int n) {
    int wave = (int)((blockIdx.x * blockDim.x + threadIdx.x) >> 6);
    int lane = threadIdx.x & 63;
    if (wave >= n) return;
    unsigned int u = h2[(size_t)wave * 64 + lane];
    float x0 = fmaxf(bflo(u), 0.0f);
    float x1 = fmaxf(bfhi(u), 0.0f);
    float2 wv1 = ((const float2*)w1)[lane];
    float2 wv2 = ((const float2*)w2)[lane];
    float a1 = x0 * wv1.x + x1 * wv1.y;
    float a2 = x0 * wv2.x + x1 * wv2.y;
#pragma unroll
    for (int off = 32; off > 0; off >>= 1) {
        a1 += __shfl_down(a1, off, 64);
        a2 += __shfl_down(a2, off, 64);
    }
    if (lane == 0) {
        float mu = a1 + b1[0];
        float x2 = a2 + b2[0];
        float sg = (x2 > 20.0f) ? x2 : __logf(1.0f + __expf(x2));
        out_mu[wave] = mu;
        out_sg[wave] = sg;
    }
}

__device__ __forceinline__ int lbound(const int* __restrict__ a, int n, int v) {
    int lo = 0, hi = n;
    while (lo < hi) {
        int m = (lo + hi) >> 1;
        if (a[m] < v) lo = m + 1; else hi = m;
    }
    return lo;
}

// One block per graph: block-reduce mu_all/sigma_all, apply correction. Zero atomics.
__global__ void seg_correct_kernel(const float* __restrict__ out_mu, const float* __restrict__ out_sg,
                                   const int* __restrict__ batch, float* __restrict__ out_muc, int n) {
    int g = blockIdx.x;
    int lo = lbound(batch, n, g);
    int hi = lbound(batch, n, g + 1);
    float smu = 0.0f, ssg = 0.0f;
    for (int i = lo + threadIdx.x; i < hi; i += blockDim.x) {
        smu += out_mu[i];
        ssg += out_sg[i];
    }
#pragma unroll
    for (int off = 32; off > 0; off >>= 1) {
        smu += __shfl_down(smu, off, 64);
        ssg += __shfl_down(ssg, off, 64);
    }
    __shared__ float pm[4], ps[4];
    int wave = threadIdx.x >> 6;
    int lane = threadIdx.x & 63;
    if (lane == 0) { pm[wave] = smu; ps[wave] = ssg; }
    __syncthreads();
    float tot_mu = pm[0] + pm[1] + pm[2] + pm[3];
    float tot_sg = ps[0] + ps[1] + ps[2] + ps[3];
    for (int i = lo + threadIdx.x; i < hi; i += blockDim.x) {
        out_muc[i] = out_mu[i] - tot_mu * (out_sg[i] / tot_sg);
    }
}

extern "C" void kernel_launch(void* const* d_in, const int* in_sizes, int n_in,
                              void* d_out, int out_size, void* d_ws, size_t ws_size,
                              hipStream_t stream) {
    const float* x      = (const float*)d_in[0];
    const int*   ei     = (const int*)d_in[1];
    const int*   batch  = (const int*)d_in[2];
    const float* lin0_w = (const float*)d_in[3];
    const float* ggc    = (const float*)d_in[4];
    const float* w_ih   = (const float*)d_in[5];
    const float* w_hh   = (const float*)d_in[6];
    const float* b_ih   = (const float*)d_in[7];
    const float* b_hh   = (const float*)d_in[8];
    const float* l1w    = (const float*)d_in[9];
    const float* l1b    = (const float*)d_in[10];
    const float* l2w    = (const float*)d_in[11];
    const float* l2b    = (const float*)d_in[12];

    int n = in_sizes[0] / FIN;   // 100000
    int e = in_sizes[1] / 2;     // 1600000
    const int* src = ei;
    const int* dstp = ei + e;

    float* out = (float*)d_out;
    float* out_muc = out;                              // [n]
    float* out_x1  = out + n;                          // [n*64]
    float* out_sg  = out + n + (size_t)n * EMB;        // [n]
    float* out_mu  = out_sg + n;                       // [n]

    // workspace layout (all 16B aligned)
    unsigned short* hbf0 = (unsigned short*)d_ws;                      // n*128 bf16
    unsigned short* hbf1 = hbf0 + (size_t)n * HH;                      // n*128 bf16
    unsigned short* Wfp  = hbf1 + (size_t)n * HH;                      // 4*49152 bf16
    unsigned short* whhp = Wfp + (size_t)LAYERS * 49152;               // 49152 bf16
    int*            deg      = (int*)(whhp + 49152 + 8);               // n
    int*            rowptr   = deg + n;                                // n+1
    int*            blocksum = rowptr + n + 1;                         // 64
    int*            blockoff = blocksum + 64;                          // 64
    int*            bucket_cnt = blockoff + 64;                        // MAXNB
    int*            col      = bucket_cnt + MAXNB;                     // e
    unsigned*       ebuf     = (unsigned*)hbf1;  // MAXNB*ECAP*4 = 16.8MB, aliases hbf1
                                                 // (dead before first agg write to hbf1)

    int nbuck = (n + SPAN - 1) >> SPANSHIFT;   // 196
    hipMemsetAsync(bucket_cnt, 0, MAXNB * sizeof(int), stream);

    int wave_blocks = (n * 64 + 255) / 256;
    lin0_kernel<<<wave_blocks, 256, 0, stream>>>(x, lin0_w, out_x1, hbf0, n);

    int eb = (e + 16383) / 16384;  // 98
    bucket_scatter_direct<<<eb, 1024, 0, stream>>>(src, dstp, bucket_cnt, ebuf, e);
    deg_from_buckets<<<nbuck, 256, 0, stream>>>(ebuf, bucket_cnt, deg, n);

    int nb = (n + SCAN_CHUNK) / SCAN_CHUNK;  // covers idx==n too
    scan_partial<<<nb, 256, 0, stream>>>(deg, blocksum, n);
    scan_blocksums<<<1, 64, 0, stream>>>(blocksum, blockoff, nb);
    scan_final<<<nb, 256, 0, stream>>>(deg, blockoff, rowptr, n);

    place_kernel<<<nbuck, 256, 0, stream>>>(ebuf, bucket_cnt, rowptr, col, n);

    pack_whh<<<(49152 + 255) / 256, 256, 0, stream>>>(w_hh, whhp);
    pack_wf<<<(LAYERS * 49152 + 255) / 256, 256, 0, stream>>>(ggc, w_ih, Wfp);

    // Chunk-pipelined layers: per layer, KCH+1 launches; launch k runs
    // agg(chunk k) co-scheduled with gru(chunk k-1) in one grid.
    int cs = (n + KCH - 1) / KCH;  // 25000
    unsigned short* hin = hbf0;
    unsigned short* hother = hbf1;
    for (int l = 0; l < LAYERS; ++l) {
        const unsigned short* Wl = Wfp + (size_t)l * 49152;
        for (int k = 0; k <= KCH; ++k) {
            int aLo = (k < KCH) ? k * cs : 0;
            int aHi = (k < KCH) ? ((k + 1) * cs < n ? (k + 1) * cs : n) : 0;
            int gLo = (k >= 1) ? (k - 1) * cs : 0;
            int gHi = (k >= 1) ? (k * cs < n ? k * cs : n) : 0;
            int aggB = (aHi > aLo) ? (aHi - aLo + 7) / 8 : 0;
            int gruB = (gHi > gLo) ? (gHi - gLo + TMG - 1) / TMG : 0;
            if (aggB + gruB == 0) continue;
            if (l == 0) {
                layer_chunk<1><<<aggB + gruB, 512, 0, stream>>>(
                    hin, hother, rowptr, col, Wl, whhp, b_ih, b_hh,
                    aLo, aHi, gLo, gHi, gruB);
            } else {
                layer_chunk<0><<<aggB + gruB, 512, 0, stream>>>(
                    hin, hother, rowptr, col, Wl, whhp, b_ih, b_hh,
                    aLo, aHi, gLo, gHi, gruB);
            }
        }
        // after all chunks: hother holds h_{l+1}; hin (h_l) is dead
        unsigned short* t = hin; hin = hother; hother = t;
    }
    // LAYERS=4 (even) -> final state in hbf0 (= hin after loop)

    readout_kernel<<<wave_blocks, 256, 0, stream>>>((const unsigned int*)hin, l1w, l1b, l2w, l2b,
                                                    out_mu, out_sg, n);
    seg_correct_kernel<<<GG, 256, 0, stream>>>(out_mu, out_sg, batch, out_muc, n);
}

// Round 9
// 615.134 us; speedup vs baseline: 1.3908x; 1.3142x over previous
//
#include <hip/hip_runtime.h>
#include <math.h>

#define NN 100000
#define FIN 27
#define EMB 64
#define HH 128
#define LAYERS 4
#define GG 512
#define SCAN_CHUNK 2048   // 256 threads x 8 elements
#define SPAN 512          // nodes per bucket
#define SPANSHIFT 9
#define MAXNB 256
#define ECAP 16384        // per-bucket edge slab capacity (mean ~8163)
#define LPAD_US 136       // LDS row stride in ushorts: 272B, 16B-aligned rows

typedef __attribute__((ext_vector_type(8))) short short8;
typedef __attribute__((ext_vector_type(4))) float floatx4;

__device__ __forceinline__ float sigmf(float x) { return 1.0f / (1.0f + __expf(-x)); }
__device__ __forceinline__ float tanhfast(float x) { return 1.0f - 2.0f / (__expf(2.0f * x) + 1.0f); }

__device__ __forceinline__ unsigned short f2bf(float f) {
    unsigned int u = __float_as_uint(f);
    u += 0x7FFFu + ((u >> 16) & 1u);
    return (unsigned short)(u >> 16);
}

__device__ __forceinline__ float bflo(unsigned int v) { return __uint_as_float(v << 16); }
__device__ __forceinline__ float bfhi(unsigned int v) { return __uint_as_float(v & 0xFFFF0000u); }
__device__ __forceinline__ float bfs(unsigned short v) { return __uint_as_float(((unsigned)v) << 16); }

// x1 = sigmoid(x @ lin0_w). REWRITE vs R0 (which ran 50us, hidden #2 cost):
// R0 issued 27 broadcast x-loads + 27 w-loads per NODE (w reloaded per wave
// though globally constant; x read 64x redundantly) -> request-issue bound at
// 900 GB/s. Now: w held in 27 regs per lane (loaded once per wave), x row read
// by ONE coalesced wave-load (lanes 0..26) + shfl broadcast; grid-stride.
// Upper-half h zeros dropped: fused layer<1> stages its own zeros.
__global__ __launch_bounds__(256)
void lin0_kernel(const float* __restrict__ x, const float* __restrict__ w,
                 float* __restrict__ x1_out, unsigned short* __restrict__ hbf, int n) {
    int gwave = (int)((blockIdx.x * blockDim.x + threadIdx.x) >> 6);
    int lane = threadIdx.x & 63;
    int nwaves = (int)((gridDim.x * blockDim.x) >> 6);
    float wreg[FIN];
#pragma unroll
    for (int k = 0; k < FIN; ++k) wreg[k] = w[k * EMB + lane];  // lane < EMB=64
    for (int i = gwave; i < n; i += nwaves) {
        float xv = (lane < FIN) ? x[(size_t)i * FIN + lane] : 0.0f;
        float acc = 0.0f;
#pragma unroll
        for (int k = 0; k < FIN; ++k) acc += __shfl(xv, k, 64) * wreg[k];
        float v = 1.0f / (1.0f + expf(-acc));
        x1_out[(size_t)i * EMB + lane] = v;
        hbf[(size_t)i * HH + lane] = f2bf(v);
    }
}

// Direct-reservation bucketed scatter: one pass over edges. Per-block LDS hist,
// one global atomic per (block,bucket), packed (dst_local<<17)|src into slab b*ECAP.
// 8192 edges/block -> 196 blocks (was 98: half the chip idle).
__global__ void bucket_scatter_direct(const int* __restrict__ src, const int* __restrict__ dst,
                                      int* __restrict__ bucket_cnt, unsigned* __restrict__ ebuf,
                                      int e) {
    __shared__ int lh[MAXNB];
    __shared__ int gb[MAXNB];
    int t = threadIdx.x;  // 1024
    for (int i = t; i < MAXNB; i += 1024) lh[i] = 0;
    __syncthreads();
    int base = blockIdx.x * 8192;
    int lidx[8], sv[8], dv[8];
#pragma unroll
    for (int i = 0; i < 8; ++i) {
        int eid = base + i * 1024 + t;
        if (eid < e) {
            sv[i] = src[eid];
            dv[i] = dst[eid];
            lidx[i] = atomicAdd(&lh[dv[i] >> SPANSHIFT], 1);
        } else lidx[i] = -1;
    }
    __syncthreads();
    for (int i = t; i < MAXNB; i += 1024) {
        int c = lh[i];
        gb[i] = c ? atomicAdd(&bucket_cnt[i], c) : 0;
    }
    __syncthreads();
#pragma unroll
    for (int i = 0; i < 8; ++i) {
        if (lidx[i] >= 0) {
            int b = dv[i] >> SPANSHIFT;
            int pos = gb[b] + lidx[i];
            if (pos < ECAP) {
                unsigned dl = (unsigned)(dv[i] - (b << SPANSHIFT));
                ebuf[(size_t)b * ECAP + pos] = (dl << 17) | (unsigned)sv[i];
            }
        }
    }
}

// Per-node degree via per-bucket LDS histogram.
__global__ void deg_from_buckets(const unsigned* __restrict__ ebuf, const int* __restrict__ bucket_cnt,
                                 int* __restrict__ deg, int n) {
    __shared__ int ld[SPAN];
    int b = blockIdx.x, t = threadIdx.x;  // 256
    ld[t] = 0; ld[t + 256] = 0;
    __syncthreads();
    int cnt = bucket_cnt[b];
    if (cnt > ECAP) cnt = ECAP;
    size_t base = (size_t)b * ECAP;
    int nodebase = b << SPANSHIFT;
    for (int j = t; j < cnt; j += 256)
        atomicAdd(&ld[ebuf[base + j] >> 17], 1);
    __syncthreads();
    int i0 = nodebase + t, i1 = nodebase + 256 + t;
    if (i0 < n) deg[i0] = ld[t];
    if (i1 < n) deg[i1] = ld[t + 256];
}

// ---- multi-block exclusive scan of deg -> rowptr ----
__global__ void scan_partial(const int* __restrict__ deg, int* __restrict__ blocksum, int n) {
    int b = blockIdx.x, t = threadIdx.x;
    int base = b * SCAN_CHUNK + t * 8;
    int s = 0;
#pragma unroll
    for (int i = 0; i < 8; ++i) {
        int idx = base + i;
        if (idx < n) s += deg[idx];
    }
#pragma unroll
    for (int off = 32; off > 0; off >>= 1) s += __shfl_down(s, off, 64);
    __shared__ int ws[4];
    if ((t & 63) == 0) ws[t >> 6] = s;
    __syncthreads();
    if (t == 0) blocksum[b] = ws[0] + ws[1] + ws[2] + ws[3];
}

__global__ void scan_blocksums(const int* __restrict__ blocksum, int* __restrict__ blockoff, int nb) {
    int t = threadIdx.x;
    int own = (t < nb) ? blocksum[t] : 0;
    int v = own;
    for (int off = 1; off < 64; off <<= 1) {
        int u = __shfl_up(v, off, 64);
        if (t >= off) v += u;
    }
    if (t < nb) blockoff[t] = v - own;
}

__global__ void scan_final(const int* __restrict__ deg, const int* __restrict__ blockoff,
                           int* __restrict__ rowptr, int n) {
    int b = blockIdx.x, t = threadIdx.x;
    int base = b * SCAN_CHUNK + t * 8;
    int v[8];
    int s = 0;
#pragma unroll
    for (int i = 0; i < 8; ++i) {
        int idx = base + i;
        v[i] = (idx < n) ? deg[idx] : 0;
        s += v[i];
    }
    __shared__ int ts[256];
    ts[t] = s;
    __syncthreads();
    for (int off = 1; off < 256; off <<= 1) {
        int u = (t >= off) ? ts[t - off] : 0;
        __syncthreads();
        ts[t] += u;
        __syncthreads();
    }
    int run = blockoff[b] + ((t == 0) ? 0 : ts[t - 1]);
#pragma unroll
    for (int i = 0; i < 8; ++i) {
        int idx = base + i;
        if (idx < n) {
            rowptr[idx] = run;
            run += v[i];
        } else if (idx == n) {
            rowptr[n] = run;
        }
    }
}

// Place edges into CSR col with LDS cursors; writes confined to ~32KB/bucket.
__global__ void place_kernel(const unsigned* __restrict__ ebuf, const int* __restrict__ bucket_cnt,
                             const int* __restrict__ rowptr, int* __restrict__ col, int n) {
    __shared__ int cur[SPAN];
    int b = blockIdx.x, t = threadIdx.x;  // 256
    int nodebase = b << SPANSHIFT;
    int i0 = nodebase + t, i1 = nodebase + 256 + t;
    cur[t] = (i0 < n) ? rowptr[i0] : 0;
    cur[t + 256] = (i1 < n) ? rowptr[i1] : 0;
    __syncthreads();
    int cnt = bucket_cnt[b];
    if (cnt > ECAP) cnt = ECAP;
    size_t base = (size_t)b * ECAP;
    for (int j = t; j < cnt; j += 256) {
        unsigned ed = ebuf[base + j];
        int pos = atomicAdd(&cur[ed >> 17], 1);
        col[pos] = (int)(ed & 0x1FFFFu);
    }
}

// Pack whh^T into MFMA B-fragment order.
__global__ void pack_whh(const float* __restrict__ w_hh, unsigned short* __restrict__ whhp) {
    int id = blockIdx.x * blockDim.x + threadIdx.x;
    if (id >= 4 * 24 * 64 * 8) return;
    int j = id & 7;
    int lane = (id >> 3) & 63;
    int ctkt = id >> 9;
    int ct = ctkt % 24;
    int kt = ctkt / 24;
    int k = kt * 32 + (lane >> 4) * 8 + j;
    int col = ct * 16 + (lane & 15);
    whhp[id] = f2bf(w_hh[col * HH + k]);
}

// Wf[l] = ggc[l] @ w_ih^T, packed in MFMA B-fragment order (bf16).
__global__ void pack_wf(const float* __restrict__ ggc, const float* __restrict__ w_ih,
                        unsigned short* __restrict__ Wfp) {
    int id = blockIdx.x * blockDim.x + threadIdx.x;
    if (id >= LAYERS * 4 * 24 * 64 * 8) return;
    int l = id / 49152;
    int rem = id % 49152;
    int j = rem & 7;
    int lane = (rem >> 3) & 63;
    int ctkt = rem >> 9;
    int ct = ctkt % 24;
    int kt = ctkt / 24;
    int k = kt * 32 + (lane >> 4) * 8 + j;
    int col = ct * 16 + (lane & 15);
    const float4* gr = (const float4*)(ggc + ((size_t)l * HH + k) * HH);
    const float4* wr = (const float4*)(w_ih + (size_t)col * HH);
    float acc = 0.0f;
#pragma unroll 4
    for (int q = 0; q < HH / 4; ++q) {
        float4 g = gr[q], w = wr[q];
        acc += g.x * w.x + g.y * w.y + g.z * w.z + g.w * w.w;
    }
    Wfp[id] = f2bf(acc);
}

// Fused layer (R0-proven, 117us/layer): gather-aggregate (LDS) + GEMM(MFMA) +
// GRU epilogue. Block = 512 thr (8 waves) = 16 nodes; wave gathers 2 nodes,
// computes ct = {w, w+8, w+16} for gi and gh, epilogue fully in-wave.
// Cross-block phase overlap (gather-phase blocks co-resident with GEMM-phase
// blocks) is what beat the split variants (R1-R7 all >= this).
template <int HALF>
__global__ __launch_bounds__(512)
void layer_kernel(const unsigned short* __restrict__ hin,
                  unsigned short* __restrict__ hout,
                  const int* __restrict__ rowptr, const int* __restrict__ col,
                  const unsigned short* __restrict__ Wfp,
                  const unsigned short* __restrict__ whhp,
                  const float* __restrict__ b_ih, const float* __restrict__ b_hh,
                  int n) {
    __shared__ unsigned short aggL[16 * LPAD_US];  // agg rows; reused for h_new in epilogue
    __shared__ unsigned short hL[16 * LPAD_US];    // staged hin rows
    int wave = threadIdx.x >> 6;   // 0..7
    int lane = threadIdx.x & 63;
    int quad = lane >> 4;
    int l15 = lane & 15;
    int lg = quad, l16 = l15;
    int M0 = blockIdx.x * 16;
    if (M0 >= n) return;
    const uint4* hin4 = (const uint4*)hin;
    const uint2* hin2 = (const uint2*)hin;

    // stage hin rows: threads 0-255 load 16 rows x 16 uint4 (upper half zero if HALF)
    if (threadIdx.x < 256) {
        int row = threadIdx.x >> 4;
        int q = threadIdx.x & 15;
        if (M0 + row < n) {
            uint4 v;
            if (HALF && q >= 8) v = make_uint4(0, 0, 0, 0);
            else v = hin4[(size_t)(M0 + row) * 16 + q];
            *(uint4*)(&hL[row * LPAD_US + q * 8]) = v;
            if (HALF && q >= 8) *(uint4*)(&aggL[row * LPAD_US + q * 8]) = make_uint4(0, 0, 0, 0);
        }
    }

    // prefetch rowptr[nb2..nb2+2] across lanes, broadcast via shfl
    int nb2 = M0 + wave * 2;
    int rp;
    {
        int idx = nb2 + lane;
        if (lane > 2 || idx > n) idx = n;
        rp = rowptr[idx];
    }

    // gather-aggregate: wave handles nodes [nb2, nb2+2)
    for (int i = 0; i < 2; ++i) {
        int node = nb2 + i;
        int r0 = __shfl(rp, i, 64);
        int r1 = __shfl(rp, i + 1, 64);
        if (node >= n) r1 = r0;
        if (HALF) {
            // 128B rows: lane l16 covers channels [l16*4, l16*4+4) via uint2
            float a[4], b[4];
#pragma unroll
            for (int k = 0; k < 4; ++k) { a[k] = 0.0f; b[k] = 0.0f; }
            int j = r0 + lg;
            for (; j + 4 < r1; j += 8) {
                int s0 = col[j], s1 = col[j + 4];
                uint2 v0 = hin2[(size_t)s0 * 32 + l16];
                uint2 v1 = hin2[(size_t)s1 * 32 + l16];
                a[0] += bflo(v0.x); a[1] += bfhi(v0.x);
                a[2] += bflo(v0.y); a[3] += bfhi(v0.y);
                b[0] += bflo(v1.x); b[1] += bfhi(v1.x);
                b[2] += bflo(v1.y); b[3] += bfhi(v1.y);
            }
            for (; j < r1; j += 4) {
                int s = col[j];
                uint2 v = hin2[(size_t)s * 32 + l16];
                a[0] += bflo(v.x); a[1] += bfhi(v.x);
                a[2] += bflo(v.y); a[3] += bfhi(v.y);
            }
#pragma unroll
            for (int k = 0; k < 4; ++k) {
                a[k] += b[k];
                a[k] += __shfl_xor(a[k], 32, 64);
                a[k] += __shfl_xor(a[k], 16, 64);
            }
            if (lg == 0 && node < n) {
                uint2 o;
                o.x = (unsigned)f2bf(a[0]) | ((unsigned)f2bf(a[1]) << 16);
                o.y = (unsigned)f2bf(a[2]) | ((unsigned)f2bf(a[3]) << 16);
                *(uint2*)(&aggL[(wave * 2 + i) * LPAD_US + l16 * 4]) = o;
            }
        } else {
            float a[8], b[8];
#pragma unroll
            for (int k = 0; k < 8; ++k) { a[k] = 0.0f; b[k] = 0.0f; }
            int j = r0 + lg;
            for (; j + 12 < r1; j += 16) {
                int s0 = col[j], s1 = col[j + 4], s2 = col[j + 8], s3 = col[j + 12];
                uint4 v0 = hin4[(size_t)s0 * 16 + l16];
                uint4 v1 = hin4[(size_t)s1 * 16 + l16];
                uint4 v2 = hin4[(size_t)s2 * 16 + l16];
                uint4 v3 = hin4[(size_t)s3 * 16 + l16];
                a[0] += bflo(v0.x); a[1] += bfhi(v0.x);
                a[2] += bflo(v0.y); a[3] += bfhi(v0.y);
                a[4] += bflo(v0.z); a[5] += bfhi(v0.z);
                a[6] += bflo(v0.w); a[7] += bfhi(v0.w);
                b[0] += bflo(v1.x); b[1] += bfhi(v1.x);
                b[2] += bflo(v1.y); b[3] += bfhi(v1.y);
                b[4] += bflo(v1.z); b[5] += bfhi(v1.z);
                b[6] += bflo(v1.w); b[7] += bfhi(v1.w);
                a[0] += bflo(v2.x); a[1] += bfhi(v2.x);
                a[2] += bflo(v2.y); a[3] += bfhi(v2.y);
                a[4] += bflo(v2.z); a[5] += bfhi(v2.z);
                a[6] += bflo(v2.w); a[7] += bfhi(v2.w);
                b[0] += bflo(v3.x); b[1] += bfhi(v3.x);
                b[2] += bflo(v3.y); b[3] += bfhi(v3.y);
                b[4] += bflo(v3.z); b[5] += bfhi(v3.z);
                b[6] += bflo(v3.w); b[7] += bfhi(v3.w);
            }
            for (; j + 4 < r1; j += 8) {
                int s0 = col[j], s1 = col[j + 4];
                uint4 v0 = hin4[(size_t)s0 * 16 + l16];
                uint4 v1 = hin4[(size_t)s1 * 16 + l16];
                a[0] += bflo(v0.x); a[1] += bfhi(v0.x);
                a[2] += bflo(v0.y); a[3] += bfhi(v0.y);
                a[4] += bflo(v0.z); a[5] += bfhi(v0.z);
                a[6] += bflo(v0.w); a[7] += bfhi(v0.w);
                b[0] += bflo(v1.x); b[1] += bfhi(v1.x);
                b[2] += bflo(v1.y); b[3] += bfhi(v1.y);
                b[4] += bflo(v1.z); b[5] += bfhi(v1.z);
                b[6] += bflo(v1.w); b[7] += bfhi(v1.w);
            }
            for (; j < r1; j += 4) {
                int s = col[j];
                uint4 v = hin4[(size_t)s * 16 + l16];
                a[0] += bflo(v.x); a[1] += bfhi(v.x);
                a[2] += bflo(v.y); a[3] += bfhi(v.y);
                a[4] += bflo(v.z); a[5] += bfhi(v.z);
                a[6] += bflo(v.w); a[7] += bfhi(v.w);
            }
#pragma unroll
            for (int k = 0; k < 8; ++k) {
                a[k] += b[k];
                a[k] += __shfl_xor(a[k], 32, 64);
                a[k] += __shfl_xor(a[k], 16, 64);
            }
            if (lg == 0 && node < n) {
                uint4 o;
                o.x = (unsigned)f2bf(a[0]) | ((unsigned)f2bf(a[1]) << 16);
                o.y = (unsigned)f2bf(a[2]) | ((unsigned)f2bf(a[3]) << 16);
                o.z = (unsigned)f2bf(a[4]) | ((unsigned)f2bf(a[5]) << 16);
                o.w = (unsigned)f2bf(a[6]) | ((unsigned)f2bf(a[7]) << 16);
                *(uint4*)(&aggL[(wave * 2 + i) * LPAD_US + l16 * 8]) = o;
            }
        }
    }

    __syncthreads();  // aggL + hL fully staged

    floatx4 acc_gi[3];
    floatx4 acc_gh[3];
#pragma unroll
    for (int g = 0; g < 3; ++g) {
        acc_gi[g] = (floatx4)0.0f;
        acc_gh[g] = (floatx4)0.0f;
    }

    const int KTMAX = HALF ? 2 : 4;
#pragma unroll
    for (int kt = 0; kt < KTMAX; ++kt) {
        int kbase = kt * 32 + quad * 8;
        int lrow = l15 * LPAD_US + kbase;
        short8 a_a = *(const short8*)(&aggL[lrow]);
        short8 a_h = *(const short8*)(&hL[lrow]);
#pragma unroll
        for (int g = 0; g < 3; ++g) {
            int ct = g * 8 + wave;
            size_t boff = ((size_t)(kt * 24 + ct) * 64 + lane) * 8;
            short8 bi = *(const short8*)(Wfp + boff);
            short8 bh = *(const short8*)(whhp + boff);
            acc_gi[g] = __builtin_amdgcn_mfma_f32_16x16x32_bf16(a_a, bi, acc_gi[g], 0, 0, 0);
            acc_gh[g] = __builtin_amdgcn_mfma_f32_16x16x32_bf16(a_h, bh, acc_gh[g], 0, 0, 0);
        }
    }

    __syncthreads();  // K-loop reads of aggL done; safe to overwrite with h_new

    {
        int c = wave * 16 + l15;
        float bir = b_ih[c], biz = b_ih[128 + c], bin_ = b_ih[256 + c];
        float bhr = b_hh[c], bhz = b_hh[128 + c], bhn = b_hh[256 + c];
#pragma unroll
        for (int j = 0; j < 4; ++j) {
            int nl = quad * 4 + j;     // local node
            int lidx = nl * LPAD_US + c;
            float gir = acc_gi[0][j] + bir;
            float ghr = acc_gh[0][j] + bhr;
            float giz = acc_gi[1][j] + biz;
            float ghz = acc_gh[1][j] + bhz;
            float gin = acc_gi[2][j] + bin_;
            float ghn = acc_gh[2][j] + bhn;
            float rr = sigmf(gir + ghr);
            float zz = sigmf(giz + ghz);
            float nn = tanhfast(gin + rr * ghn);
            float hp = bfs(hL[lidx]);
            aggL[lidx] = f2bf((1.0f - zz) * nn + zz * hp);
        }
    }

    __syncthreads();

    // coalesced store of h_new to hout: threads 0-255 store 16 rows x 16 uint4
    if (threadIdx.x < 256) {
        int row = threadIdx.x >> 4;
        int q = threadIdx.x & 15;
        if (M0 + row < n) {
            uint4 v = *(const uint4*)(&aggL[row * LPAD_US + q * 8]);
            *(uint4*)(hout + (size_t)(M0 + row) * HH + q * 8) = v;
        }
    }
}

// Per-node mu/sigma from bf16 h. One wave per node, lane = 2 channels.
__global__ void readout_kernel(const unsigned int* __restrict__ h2, const float* __restrict__ w1,
                               const float* __restrict__ b1, const float* __restrict__ w2,
                               const float* __restrict__ b2,
                               float* __restrict__ out_mu, float* __restrict__ out_sg, int n) {
    int wave = (int)((blockIdx.x * blockDim.x + threadIdx.x) >> 6);
    int lane = threadIdx.x & 63;
    if (wave >= n) return;
    unsigned int u = h2[(size_t)wave * 64 + lane];
    float x0 = fmaxf(bflo(u), 0.0f);
    float x1 = fmaxf(bfhi(u), 0.0f);
    float2 wv1 = ((const float2*)w1)[lane];
    float2 wv2 = ((const float2*)w2)[lane];
    float a1 = x0 * wv1.x + x1 * wv1.y;
    float a2 = x0 * wv2.x + x1 * wv2.y;
#pragma unroll
    for (int off = 32; off > 0; off >>= 1) {
        a1 += __shfl_down(a1, off, 64);
        a2 += __shfl_down(a2, off, 64);
    }
    if (lane == 0) {
        float mu = a1 + b1[0];
        float x2 = a2 + b2[0];
        float sg = (x2 > 20.0f) ? x2 : __logf(1.0f + __expf(x2));
        out_mu[wave] = mu;
        out_sg[wave] = sg;
    }
}

__device__ __forceinline__ int lbound(const int* __restrict__ a, int n, int v) {
    int lo = 0, hi = n;
    while (lo < hi) {
        int m = (lo + hi) >> 1;
        if (a[m] < v) lo = m + 1; else hi = m;
    }
    return lo;
}

// One block per graph: block-reduce mu_all/sigma_all, apply correction. Zero atomics.
__global__ void seg_correct_kernel(const float* __restrict__ out_mu, const float* __restrict__ out_sg,
                                   const int* __restrict__ batch, float* __restrict__ out_muc, int n) {
    int g = blockIdx.x;
    int lo = lbound(batch, n, g);
    int hi = lbound(batch, n, g + 1);
    float smu = 0.0f, ssg = 0.0f;
    for (int i = lo + threadIdx.x; i < hi; i += blockDim.x) {
        smu += out_mu[i];
        ssg += out_sg[i];
    }
#pragma unroll
    for (int off = 32; off > 0; off >>= 1) {
        smu += __shfl_down(smu, off, 64);
        ssg += __shfl_down(ssg, off, 64);
    }
    __shared__ float pm[4], ps[4];
    int wave = threadIdx.x >> 6;
    int lane = threadIdx.x & 63;
    if (lane == 0) { pm[wave] = smu; ps[wave] = ssg; }
    __syncthreads();
    float tot_mu = pm[0] + pm[1] + pm[2] + pm[3];
    float tot_sg = ps[0] + ps[1] + ps[2] + ps[3];
    for (int i = lo + threadIdx.x; i < hi; i += blockDim.x) {
        out_muc[i] = out_mu[i] - tot_mu * (out_sg[i] / tot_sg);
    }
}

extern "C" void kernel_launch(void* const* d_in, const int* in_sizes, int n_in,
                              void* d_out, int out_size, void* d_ws, size_t ws_size,
                              hipStream_t stream) {
    const float* x      = (const float*)d_in[0];
    const int*   ei     = (const int*)d_in[1];
    const int*   batch  = (const int*)d_in[2];
    const float* lin0_w = (const float*)d_in[3];
    const float* ggc    = (const float*)d_in[4];
    const float* w_ih   = (const float*)d_in[5];
    const float* w_hh   = (const float*)d_in[6];
    const float* b_ih   = (const float*)d_in[7];
    const float* b_hh   = (const float*)d_in[8];
    const float* l1w    = (const float*)d_in[9];
    const float* l1b    = (const float*)d_in[10];
    const float* l2w    = (const float*)d_in[11];
    const float* l2b    = (const float*)d_in[12];

    int n = in_sizes[0] / FIN;   // 100000
    int e = in_sizes[1] / 2;     // 1600000
    const int* src = ei;
    const int* dstp = ei + e;

    float* out = (float*)d_out;
    float* out_muc = out;                              // [n]
    float* out_x1  = out + n;                          // [n*64]
    float* out_sg  = out + n + (size_t)n * EMB;        // [n]
    float* out_mu  = out_sg + n;                       // [n]

    // workspace layout (all 16B aligned)
    unsigned short* hbf0 = (unsigned short*)d_ws;                      // n*128 bf16
    unsigned short* hbf1 = hbf0 + (size_t)n * HH;                      // n*128 bf16
    unsigned short* Wfp  = hbf1 + (size_t)n * HH;                      // 4*49152 bf16
    unsigned short* whhp = Wfp + (size_t)LAYERS * 49152;               // 49152 bf16
    int*            deg      = (int*)(whhp + 49152 + 8);               // n
    int*            rowptr   = deg + n;                                // n+1
    int*            blocksum = rowptr + n + 1;                         // 64
    int*            blockoff = blocksum + 64;                          // 64
    int*            bucket_cnt = blockoff + 64;                        // MAXNB
    int*            col      = bucket_cnt + MAXNB;                     // e
    unsigned*       ebuf     = (unsigned*)hbf1;  // MAXNB*ECAP*4 = 16.8MB, aliases hbf1
                                                 // (dead before first layer write to hbf1)

    int nbuck = (n + SPAN - 1) >> SPANSHIFT;   // 196
    hipMemsetAsync(bucket_cnt, 0, MAXNB * sizeof(int), stream);

    lin0_kernel<<<2048, 256, 0, stream>>>(x, lin0_w, out_x1, hbf0, n);

    int eb = (e + 8191) / 8192;  // 196
    bucket_scatter_direct<<<eb, 1024, 0, stream>>>(src, dstp, bucket_cnt, ebuf, e);
    deg_from_buckets<<<nbuck, 256, 0, stream>>>(ebuf, bucket_cnt, deg, n);

    int nb = (n + SCAN_CHUNK) / SCAN_CHUNK;  // covers idx==n too
    scan_partial<<<nb, 256, 0, stream>>>(deg, blocksum, n);
    scan_blocksums<<<1, 64, 0, stream>>>(blocksum, blockoff, nb);
    scan_final<<<nb, 256, 0, stream>>>(deg, blockoff, rowptr, n);

    place_kernel<<<nbuck, 256, 0, stream>>>(ebuf, bucket_cnt, rowptr, col, n);

    pack_whh<<<(49152 + 255) / 256, 256, 0, stream>>>(w_hh, whhp);
    pack_wf<<<(LAYERS * 49152 + 255) / 256, 256, 0, stream>>>(ggc, w_ih, Wfp);

    int gru_blocks = (n + 15) / 16;  // 6250
    unsigned short* hin = hbf0;
    unsigned short* hout = hbf1;
    for (int l = 0; l < LAYERS; ++l) {
        if (l == 0) {
            layer_kernel<1><<<gru_blocks, 512, 0, stream>>>(hin, hout, rowptr, col,
                                                            Wfp, whhp, b_ih, b_hh, n);
        } else {
            layer_kernel<0><<<gru_blocks, 512, 0, stream>>>(hin, hout, rowptr, col,
                                                            Wfp + (size_t)l * 49152, whhp,
                                                            b_ih, b_hh, n);
        }
        unsigned short* t = hin; hin = hout; hout = t;
    }
    // LAYERS=4 (even) -> final state in hbf0 (= hin after loop)

    int wave_blocks = (n * 64 + 255) / 256;
    readout_kernel<<<wave_blocks, 256, 0, stream>>>((const unsigned int*)hin, l1w, l1b, l2w, l2b,
                                                    out_mu, out_sg, n);
    seg_correct_kernel<<<GG, 256, 0, stream>>>(out_mu, out_sg, batch, out_muc, n);
}